// Round 9
// baseline (1624.112 us; speedup 1.0000x reference)
//
#include <hip/hip_runtime.h>

typedef unsigned short u16;
typedef short bf16x8 __attribute__((ext_vector_type(8)));
typedef float f32x4 __attribute__((ext_vector_type(4)));
typedef unsigned short u16x4 __attribute__((ext_vector_type(4)));
typedef unsigned short u16x8 __attribute__((ext_vector_type(8)));
typedef unsigned int u32x2 __attribute__((ext_vector_type(2)));

#define B_ 2
#define T_ 2048
#define C_ 512
#define H_ 8
#define FF_ 2048
#define L_ 6
#define V_ 50257
#define M_ (B_*T_)

__device__ __forceinline__ u16 f2b(float f) {
  union { float f; unsigned u; } v; v.f = f;
  unsigned r = v.u + 0x7FFFu + ((v.u >> 16) & 1u);
  return (u16)(r >> 16);
}
__device__ __forceinline__ float b2f(u16 u) {
  union { unsigned u; float f; } v; v.u = ((unsigned)u) << 16; return v.f;
}
__device__ __forceinline__ unsigned pk_bf16(float lo, float hi) {
  unsigned r;
  asm volatile("v_cvt_pk_bf16_f32 %0, %1, %2" : "=v"(r) : "v"(lo), "v"(hi));
  return r;
}
__device__ __forceinline__ float exp2_fast(float x) {
  float r; asm("v_exp_f32 %0, %1" : "=v"(r) : "v"(x)); return r;
}
__device__ __forceinline__ float rcp_fast(float x) {
  float r; asm("v_rcp_f32 %0, %1" : "=v"(r) : "v"(x)); return r;
}

__device__ __forceinline__ void async16(const void* g, void* l) {
  __builtin_amdgcn_global_load_lds((const __attribute__((address_space(1))) unsigned int*)g,
                                   (__attribute__((address_space(3))) unsigned int*)l, 16, 0, 0);
}

template<int N> __device__ __forceinline__ void vwait() {
  if constexpr (N == 0) asm volatile("s_waitcnt vmcnt(0)" ::: "memory");
  else if constexpr (N == 2) asm volatile("s_waitcnt vmcnt(2)" ::: "memory");
  else if constexpr (N == 3) asm volatile("s_waitcnt vmcnt(3)" ::: "memory");
  else if constexpr (N == 4) asm volatile("s_waitcnt vmcnt(4)" ::: "memory");
}

__device__ __forceinline__ bf16x8 scale8(u16x8 v, float s) {
  union { bf16x8 b; unsigned u[4]; } r;
#pragma unroll
  for (int i = 0; i < 4; i++)
    r.u[i] = pk_bf16(b2f(v[2*i]) * s, b2f(v[2*i+1]) * s);
  return r.b;
}

__device__ __forceinline__ float gelu_f(float f) {
  float u = f * f;
  float inner = f * (0.7978845608028654f + 0.03567740814183056f * u);
  inner = fminf(fmaxf(inner, -15.f), 15.f);
  float a = exp2_fast(2.8853900817779268f * inner);
  return f * a * rcp_fast(a + 1.0f);
}

// ---------------- fp32 -> bf16 conversion (all 5 weight tensors, 1 launch) ----
struct CvtArgs { const f32x4* s[5]; u16x4* d[5]; };
__global__ void cvt_all_k(CvtArgs a) {
  const int sizes[5] = { V_*C_/4, L_*3*C_*C_/4, L_*C_*C_/4, L_*FF_*C_/4, L_*C_*FF_/4 };
  int gid = blockIdx.x * blockDim.x + threadIdx.x;
  int stride = gridDim.x * blockDim.x;
#pragma unroll
  for (int seg = 0; seg < 5; seg++) {
    const f32x4* src = a.s[seg];
    u16x4* dst = a.d[seg];
    for (int i = gid; i < sizes[seg]; i += stride) {
      f32x4 v = src[i];
      u16x4 o;
      o[0] = f2b(v[0]); o[1] = f2b(v[1]); o[2] = f2b(v[2]); o[3] = f2b(v[3]);
      dst[i] = o;
    }
  }
}

// ---------------- embedding ----------------
__global__ void embed_k(const int* __restrict__ idx, const float* __restrict__ wte,
                        const float* __restrict__ wpe, float* __restrict__ x) {
  int t = blockIdx.x * 256 + threadIdx.x;
  int row = t >> 7;
  int c4 = t & 127;
  int tok = idx[row];
  int pos = row & (T_ - 1);
  f32x4 a = ((const f32x4*)(wte + (long)tok * C_))[c4];
  f32x4 p = ((const f32x4*)(wpe + (long)pos * C_))[c4];
  ((f32x4*)x)[t] = a + p;
}

// ---------------- layernorm ----------------
__global__ void ln_k(const float* __restrict__ x, const float* __restrict__ w,
                     const float* __restrict__ b, u16* __restrict__ out) {
  int wv = threadIdx.x >> 6;
  int lane = threadIdx.x & 63;
  int row = blockIdx.x * 4 + wv;
  const f32x4* xr = (const f32x4*)(x + (long)row * C_);
  f32x4 v0 = xr[lane * 2], v1 = xr[lane * 2 + 1];
  float s = 0.f, s2 = 0.f;
#pragma unroll
  for (int j = 0; j < 4; j++) { s += v0[j] + v1[j]; s2 += v0[j]*v0[j] + v1[j]*v1[j]; }
#pragma unroll
  for (int off = 32; off >= 1; off >>= 1) { s += __shfl_xor(s, off); s2 += __shfl_xor(s2, off); }
  float mu = s * (1.f / C_);
  float inv = rsqrtf(s2 * (1.f / C_) - mu * mu + 1e-5f);
  const f32x4* wr = (const f32x4*)w;
  const f32x4* br = (const f32x4*)b;
  f32x4 w0 = wr[lane*2], w1 = wr[lane*2+1], b0 = br[lane*2], b1 = br[lane*2+1];
  u16x8 o;
#pragma unroll
  for (int j = 0; j < 4; j++) {
    o[j]     = f2b((v0[j] - mu) * inv * w0[j] + b0[j]);
    o[j + 4] = f2b((v1[j] - mu) * inv * w1[j] + b1[j]);
  }
  *(u16x8*)(out + (long)row * C_ + lane * 8) = o;
}

// ---------------- GEMM BK=64: C[M,N] = A[M,K] * B[N,K]^T ----------------
// 3-buffer single-barrier ring, counted vmcnt. Per-half slot swizzle:
// staging slot sl (0..7) of row r holds global k-chunk (sl&4)|((sl&3)^(r&3));
// read slot (g^(r&3))+4h recovers chunk 4h|g.
// EPI: 0 = bf16 store, 1 = fp32 residual RMW, 2 = gelu->bf16
template<int EPI, int BM, int BN>
__global__ __launch_bounds__(256) void gemm64_k(
    const u16* __restrict__ A, const u16* __restrict__ Bw,
    u16* __restrict__ Cb, float* __restrict__ Cf,
    int N, int K, int ldc)
{
  constexpr int MT = BM / 32;          // per-wave m-tiles (wave = BM/2 x BN/2)
  constexpr int NT = BN / 32;
  constexpr int AJ = BM / 32;          // A row-groups of 32 rows
  constexpr int BJ = BN / 32;
  constexpr int LPT = AJ + BJ;
  __shared__ __align__(16) u16 sA[3][BM * 64];
  __shared__ __align__(16) u16 sB[3][BN * 64];
  const int tid = threadIdx.x;
  const int n0 = blockIdx.x * BN;
  const int m0 = blockIdx.y * BM;
  const int w = tid >> 6;
  const int lane = tid & 63;
  const int wm = (w >> 1) * (BM / 2);
  const int wn = (w & 1) * (BN / 2);
  const int g = lane >> 4;
  const int l15 = lane & 15;
  const int sw3 = l15 & 3;

  f32x4 acc[MT][NT] = {};

  const int nk = K >> 6;
  const int srow = tid >> 3;           // 0..31
  const int sl = tid & 7;
  const int kcol = (((sl & 4) | ((sl & 3) ^ (srow & 3)))) * 8;
  const u16* gA[AJ];
  const u16* gB[BJ];
#pragma unroll
  for (int j = 0; j < AJ; j++)
    gA[j] = A + (long)(m0 + srow + j * 32) * K + kcol;
#pragma unroll
  for (int j = 0; j < BJ; j++)
    gB[j] = Bw + (long)(n0 + srow + j * 32) * K + kcol;

  auto stage = [&](int buf, int kt) {
    int ko = kt << 6;
#pragma unroll
    for (int j = 0; j < AJ; j++)
      async16(gA[j] + ko, &sA[buf][(j * 256 + w * 64) * 8]);
#pragma unroll
    for (int j = 0; j < BJ; j++)
      async16(gB[j] + ko, &sB[buf][(j * 256 + w * 64) * 8]);
  };

  stage(0, 0);
  stage(1, 1);
  int cur = 0, nxt = 2;
  for (int kt = 0; kt < nk; kt++) {
    if (kt + 1 < nk) vwait<LPT>(); else vwait<0>();
    __builtin_amdgcn_s_barrier();
    if (kt + 2 < nk) stage(nxt, kt + 2);
    const u16* pa = sA[cur];
    const u16* pb = sB[cur];
#pragma unroll
    for (int h = 0; h < 2; h++) {
      bf16x8 af[MT], bfr[NT];
#pragma unroll
      for (int mt = 0; mt < MT; mt++)
        af[mt] = *(const bf16x8*)(pa + (wm + mt * 16 + l15) * 64 + (((g ^ sw3) + h * 4) * 8));
#pragma unroll
      for (int nt = 0; nt < NT; nt++)
        bfr[nt] = *(const bf16x8*)(pb + (wn + nt * 16 + l15) * 64 + (((g ^ sw3) + h * 4) * 8));
#pragma unroll
      for (int mt = 0; mt < MT; mt++)
#pragma unroll
        for (int nt = 0; nt < NT; nt++)
          acc[mt][nt] = __builtin_amdgcn_mfma_f32_16x16x32_bf16(af[mt], bfr[nt], acc[mt][nt], 0, 0, 0);
    }
    cur = (cur == 2) ? 0 : cur + 1;
    nxt = (nxt == 2) ? 0 : nxt + 1;
  }

#pragma unroll
  for (int mt = 0; mt < MT; mt++) {
    int m = m0 + wm + mt * 16 + g * 4;
#pragma unroll
    for (int nt = 0; nt < NT; nt++) {
      int n = n0 + wn + nt * 16 + l15;
      f32x4 v = acc[mt][nt];
#pragma unroll
      for (int r = 0; r < 4; r++) {
        long ci = (long)(m + r) * ldc + n;
        if (EPI == 0) {
          Cb[ci] = f2b(v[r]);
        } else if (EPI == 1) {
          Cf[ci] += v[r];
        } else {
          Cb[ci] = f2b(gelu_f(v[r]));
        }
      }
    }
  }
}

// ---------------- lm_head GEMM: 256x256, 512 threads (8 waves, 64x128/wave) ----
// 3-buf ring LPT=4, grid 3152 = 8*394 XCD-bijective. NT stores on C protect
// L2/LLC for the streamed B panel (C = 823MB write-once).
__global__ __launch_bounds__(512) void gemm_lmhead_k(
    const u16* __restrict__ A, const u16* __restrict__ Bw,
    float* __restrict__ Cf, int N)
{
  __shared__ __align__(16) u16 sA[3][256 * 32];
  __shared__ __align__(16) u16 sB[3][256 * 32];
  const int K = 512;
  const int bid = blockIdx.x;
  const int swz = (bid & 7) * 394 + (bid >> 3);
  const int m0 = (swz / 197) * 256;
  const int n0 = (swz % 197) * 256;
  const int tid = threadIdx.x;
  const int w = tid >> 6;
  const int lane = tid & 63;
  const int wm = (w >> 1) * 64;
  const int wn = (w & 1) * 128;
  const int g = lane >> 4;
  const int l15 = lane & 15;
  const int sw3 = l15 & 3;

  f32x4 acc[4][8] = {};

  const int ksw = ((tid & 3) ^ ((tid >> 2) & 3)) * 8;
  const u16* gA[2];
  const u16* gB[2];
#pragma unroll
  for (int j = 0; j < 2; j++) {
    gA[j] = A + (long)(m0 + (tid >> 2) + j * 128) * K + ksw;
    int brow = n0 + (tid >> 2) + j * 128; if (brow > N - 1) brow = N - 1;
    gB[j] = Bw + (long)brow * K + ksw;
  }

  auto stage = [&](int buf, int kt) {
    int ko = kt << 5;
#pragma unroll
    for (int j = 0; j < 2; j++)
      async16(gA[j] + ko, &sA[buf][(j * 512 + w * 64) * 8]);
#pragma unroll
    for (int j = 0; j < 2; j++)
      async16(gB[j] + ko, &sB[buf][(j * 512 + w * 64) * 8]);
  };

  stage(0, 0);
  stage(1, 1);
  int cur = 0, nxt = 2;
  const int nk = K >> 5;   // 16
  for (int kt = 0; kt < nk; kt++) {
    if (kt + 1 < nk) vwait<4>(); else vwait<0>();
    __builtin_amdgcn_s_barrier();
    if (kt + 2 < nk) stage(nxt, kt + 2);
    const u16* pa = sA[cur];
    const u16* pb = sB[cur];
    bf16x8 af[4], bfr[8];
#pragma unroll
    for (int mt = 0; mt < 4; mt++)
      af[mt] = *(const bf16x8*)(pa + (wm + mt * 16 + l15) * 32 + ((g ^ sw3) * 8));
#pragma unroll
    for (int nt = 0; nt < 8; nt++)
      bfr[nt] = *(const bf16x8*)(pb + (wn + nt * 16 + l15) * 32 + ((g ^ sw3) * 8));
    __builtin_amdgcn_s_setprio(1);
#pragma unroll
    for (int mt = 0; mt < 4; mt++)
#pragma unroll
      for (int nt = 0; nt < 8; nt++)
        acc[mt][nt] = __builtin_amdgcn_mfma_f32_16x16x32_bf16(af[mt], bfr[nt], acc[mt][nt], 0, 0, 0);
    __builtin_amdgcn_s_setprio(0);
    cur = (cur == 2) ? 0 : cur + 1;
    nxt = (nxt == 2) ? 0 : nxt + 1;
  }

#pragma unroll
  for (int mt = 0; mt < 4; mt++) {
    int m = m0 + wm + mt * 16 + g * 4;
#pragma unroll
    for (int nt = 0; nt < 8; nt++) {
      int n = n0 + wn + nt * 16 + l15;
      f32x4 v = acc[mt][nt];
      if (n < N) {
#pragma unroll
        for (int r = 0; r < 4; r++)
          __builtin_nontemporal_store(v[r], &Cf[(long)(m + r) * N + n]);
      }
    }
  }
}

// ---------------- flash attention: 4 waves / 64-row qblk ----------------
__global__ __launch_bounds__(256) void attn_k(const u16* __restrict__ qkv, u16* __restrict__ out) {
  const int bh = blockIdx.y;
  const int b = bh >> 3;
  const int h = bh & 7;
  const int tid = threadIdx.x;
  const int wv = tid >> 6;
  const int lane = tid & 63;
  const int g = lane >> 4;
  const int l15 = lane & 15;
  const int qblk = 31 - blockIdx.x;

  __shared__ __align__(16) u16 Ks[2][64 * 64];
  __shared__ __align__(16) u16 Vt[2][64 * 72];
  __shared__ __align__(16) u16 Ps[4][16 * 64];

  const long base = (long)b * T_ * 1536;
  const u16* kbase = qkv + base + 512 + h * 64;
  const u16* vbase = qkv + base + 1024 + h * 64;
  const int kq = tid & 15;
  const int dg = (tid >> 4) & 7;
  const float qscale = 0.18033688011112042f;  // 1/sqrt(64) * log2(e)

  const int q0 = qblk * 64 + wv * 16;

  const u16* qrow = qkv + base + (long)(q0 + l15) * 1536 + h * 64;
  bf16x8 qf0 = scale8(*(const u16x8*)(qrow + g * 8), qscale);
  bf16x8 qf1 = scale8(*(const u16x8*)(qrow + 32 + g * 8), qscale);

  f32x4 o[4] = {};
  float mrun[4] = {-1e30f, -1e30f, -1e30f, -1e30f};
  float lrun[4] = {0.f, 0.f, 0.f, 0.f};
  const int kvend = qblk * 64 + 64;

  u16x8 vreg[4];
#pragma unroll
  for (int i = 0; i < 2; i++) {
    int chunk = i * 256 + tid;
    int row = chunk >> 3, c8 = chunk & 7;
    async16(kbase + (long)row * 1536 + (c8 ^ (row & 7)) * 8,
            &Ks[0][(i * 256 + wv * 64) * 8]);
  }
  if (tid < 128) {
#pragma unroll
    for (int t = 0; t < 4; t++)
      vreg[t] = *(const u16x8*)(vbase + (long)(kq + 16 * t) * 1536 + dg * 8);
#pragma unroll
    for (int e = 0; e < 8; e++) {
      int d = dg * 8 + e;
      u32x2 wq = { (unsigned)vreg[0][e] | ((unsigned)vreg[1][e] << 16),
                   (unsigned)vreg[2][e] | ((unsigned)vreg[3][e] << 16) };
      *(u32x2*)(&Vt[0][d * 72 + kq * 4]) = wq;
    }
  }
  __syncthreads();

  int cur = 0;
  for (int j0 = 0; j0 < kvend; j0 += 64, cur ^= 1) {
    const bool more = (j0 + 64) < kvend;
    if (more) {
      int jn = j0 + 64;
#pragma unroll
      for (int i = 0; i < 2; i++) {
        int chunk = i * 256 + tid;
        int row = chunk >> 3, c8 = chunk & 7;
        async16(kbase + (long)(jn + row) * 1536 + (c8 ^ (row & 7)) * 8,
                &Ks[cur ^ 1][(i * 256 + wv * 64) * 8]);
      }
      if (tid < 128) {
#pragma unroll
        for (int t = 0; t < 4; t++)
          vreg[t] = *(const u16x8*)(vbase + (long)(jn + kq + 16 * t) * 1536 + dg * 8);
      }
    }

    f32x4 s[4] = {};
    const u16* kp = Ks[cur];
#pragma unroll
    for (int t = 0; t < 4; t++) {
      int row = t * 16 + l15;
      const u16* kr = kp + row * 64;
      bf16x8 k0 = *(const bf16x8*)(kr + ((g ^ (row & 7)) * 8));
      bf16x8 k1 = *(const bf16x8*)(kr + (((4 + g) ^ (row & 7)) * 8));
      s[t] = __builtin_amdgcn_mfma_f32_16x16x32_bf16(qf0, k0, s[t], 0, 0, 0);
      s[t] = __builtin_amdgcn_mfma_f32_16x16x32_bf16(qf1, k1, s[t], 0, 0, 0);
    }

    const bool diag = (j0 + 64) == kvend;
    u16* pw = Ps[wv];
#pragma unroll
    for (int r = 0; r < 4; r++) {
      int row = q0 + g * 4 + r;
      float v0 = s[0][r], v1 = s[1][r], v2 = s[2][r], v3 = s[3][r];
      if (diag) {
        if (j0 +      l15 > row) v0 = -1e30f;
        if (j0 + 16 + l15 > row) v1 = -1e30f;
        if (j0 + 32 + l15 > row) v2 = -1e30f;
        if (j0 + 48 + l15 > row) v3 = -1e30f;
      }
      float mloc = fmaxf(fmaxf(v0, v1), fmaxf(v2, v3));
      float m = mrun[r];
      if (!__all(mloc <= m + 8.0f)) {
        float mx = mloc;
        mx = fmaxf(mx, __shfl_xor(mx, 1));
        mx = fmaxf(mx, __shfl_xor(mx, 2));
        mx = fmaxf(mx, __shfl_xor(mx, 4));
        mx = fmaxf(mx, __shfl_xor(mx, 8));
        float mn = fmaxf(m, mx);
        float sc2 = exp2_fast(m - mn);
        lrun[r] *= sc2;
#pragma unroll
        for (int dt = 0; dt < 4; dt++) o[dt][r] *= sc2;
        m = mn; mrun[r] = mn;
      }
      float e0 = exp2_fast(v0 - m), e1 = exp2_fast(v1 - m);
      float e2 = exp2_fast(v2 - m), e3 = exp2_fast(v3 - m);
      lrun[r] += (e0 + e1) + (e2 + e3);
      u32x2 pkq = { pk_bf16(e0, e1), pk_bf16(e2, e3) };
      int prow = g * 4 + r;
      int byt = prow * 128 + ((((l15 >> 1) ^ (prow & 7)) << 4)) + (l15 & 1) * 8;
      *(u32x2*)((char*)pw + byt) = pkq;
    }

    const u16* vt = Vt[cur];
    bf16x8 pf0 = *(const bf16x8*)((char*)pw + l15 * 128 + (((g) ^ (l15 & 7)) << 4));
    bf16x8 pf1 = *(const bf16x8*)((char*)pw + l15 * 128 + (((4 + g) ^ (l15 & 7)) << 4));
#pragma unroll
    for (int dt = 0; dt < 4; dt++) {
      int d = dt * 16 + l15;
      bf16x8 vf0 = *(const bf16x8*)(vt + d * 72 + g * 8);
      bf16x8 vf1 = *(const bf16x8*)(vt + d * 72 + 32 + g * 8);
      o[dt] = __builtin_amdgcn_mfma_f32_16x16x32_bf16(pf0, vf0, o[dt], 0, 0, 0);
      o[dt] = __builtin_amdgcn_mfma_f32_16x16x32_bf16(pf1, vf1, o[dt], 0, 0, 0);
    }

    if (more && tid < 128) {
#pragma unroll
      for (int e = 0; e < 8; e++) {
        int d = dg * 8 + e;
        u32x2 wq = { (unsigned)vreg[0][e] | ((unsigned)vreg[1][e] << 16),
                     (unsigned)vreg[2][e] | ((unsigned)vreg[3][e] << 16) };
        *(u32x2*)(&Vt[cur ^ 1][d * 72 + kq * 4]) = wq;
      }
    }
    __syncthreads();
  }

#pragma unroll
  for (int r = 0; r < 4; r++) {
    float ls = lrun[r];
    ls += __shfl_xor(ls, 1); ls += __shfl_xor(ls, 2);
    ls += __shfl_xor(ls, 4); ls += __shfl_xor(ls, 8);
    float inv = 1.0f / ls;
    int row = q0 + g * 4 + r;
    u16* orow = out + (long)(b * T_ + row) * C_ + h * 64;
#pragma unroll
    for (int dt = 0; dt < 4; dt++)
      orow[dt * 16 + l15] = f2b(o[dt][r] * inv);
  }
}

// ---------------- host launcher ----------------
extern "C" void kernel_launch(void* const* d_in, const int* in_sizes, int n_in,
                              void* d_out, int out_size, void* d_ws, size_t ws_size,
                              hipStream_t stream) {
  const int*   idx    = (const int*)  d_in[0];
  const float* wte    = (const float*)d_in[1];
  const float* wpe    = (const float*)d_in[2];
  const float* ln1w   = (const float*)d_in[3];
  const float* ln1b   = (const float*)d_in[4];
  const float* wattn  = (const float*)d_in[5];
  const float* wcproj = (const float*)d_in[6];
  const float* ln2w   = (const float*)d_in[7];
  const float* ln2b   = (const float*)d_in[8];
  const float* wfc    = (const float*)d_in[9];
  const float* wproj2 = (const float*)d_in[10];
  const float* lnfw   = (const float*)d_in[11];
  const float* lnfb   = (const float*)d_in[12];
  float* out = (float*)d_out;

  char* p = (char*)d_ws;
  size_t off = 0;
  auto alloc = [&](size_t bytes) -> void* {
    void* r = p + off; off += (bytes + 255) & ~(size_t)255; return r;
  };
  float* x    = (float*)alloc((size_t)M_ * C_ * 4);
  u16* xn     = (u16*)alloc((size_t)M_ * C_ * 2);
  u16* qkvb   = (u16*)alloc((size_t)M_ * 3 * C_ * 2);
  u16* attb   = (u16*)alloc((size_t)M_ * C_ * 2);
  u16* hb     = (u16*)alloc((size_t)M_ * FF_ * 2);
  u16* wteB   = (u16*)alloc((size_t)V_ * C_ * 2);
  u16* wattnB = (u16*)alloc((size_t)L_ * 3 * C_ * C_ * 2);
  u16* wprojB = (u16*)alloc((size_t)L_ * C_ * C_ * 2);
  u16* wfcB   = (u16*)alloc((size_t)L_ * FF_ * C_ * 2);
  u16* wp2B   = (u16*)alloc((size_t)L_ * C_ * FF_ * 2);
  if (off > ws_size) return;

  CvtArgs ca;
  ca.s[0] = (const f32x4*)wte;    ca.d[0] = (u16x4*)wteB;
  ca.s[1] = (const f32x4*)wattn;  ca.d[1] = (u16x4*)wattnB;
  ca.s[2] = (const f32x4*)wcproj; ca.d[2] = (u16x4*)wprojB;
  ca.s[3] = (const f32x4*)wfc;    ca.d[3] = (u16x4*)wfcB;
  ca.s[4] = (const f32x4*)wproj2; ca.d[4] = (u16x4*)wp2B;
  cvt_all_k<<<dim3(2048), dim3(256), 0, stream>>>(ca);

  embed_k<<<dim3(M_ * C_ / 4 / 256), dim3(256), 0, stream>>>(idx, wte, wpe, x);

  for (int l = 0; l < L_; l++) {
    ln_k<<<dim3(M_ / 4), dim3(256), 0, stream>>>(x, ln1w + l * C_, ln1b + l * C_, xn);
    gemm64_k<0, 64, 128><<<dim3(12, 64), dim3(256), 0, stream>>>(
        xn, wattnB + (size_t)l * 3 * C_ * C_, qkvb, nullptr, 3 * C_, C_, 3 * C_);
    attn_k<<<dim3(32, B_ * H_), dim3(256), 0, stream>>>(qkvb, attb);
    gemm64_k<1, 64, 64><<<dim3(8, 64), dim3(256), 0, stream>>>(
        attb, wprojB + (size_t)l * C_ * C_, nullptr, x, C_, C_, C_);
    ln_k<<<dim3(M_ / 4), dim3(256), 0, stream>>>(x, ln2w + l * C_, ln2b + l * C_, xn);
    gemm64_k<2, 128, 64><<<dim3(32, 32), dim3(256), 0, stream>>>(
        xn, wfcB + (size_t)l * FF_ * C_, hb, nullptr, FF_, C_, FF_);
    gemm64_k<1, 64, 64><<<dim3(8, 64), dim3(256), 0, stream>>>(
        hb, wp2B + (size_t)l * C_ * FF_, nullptr, x, C_, FF_, C_);
  }
  ln_k<<<dim3(M_ / 4), dim3(256), 0, stream>>>(x, lnfw, lnfb, xn);
  gemm_lmhead_k<<<dim3(16 * 197), dim3(512), 0, stream>>>(xn, wteB, out, V_);
}

// Round 10
// 1257.999 us; speedup vs baseline: 1.2910x; 1.2910x over previous
//
#include <hip/hip_runtime.h>

typedef unsigned short u16;
typedef short bf16x8 __attribute__((ext_vector_type(8)));
typedef float f32x4 __attribute__((ext_vector_type(4)));
typedef unsigned short u16x4 __attribute__((ext_vector_type(4)));
typedef unsigned short u16x8 __attribute__((ext_vector_type(8)));
typedef unsigned int u32x2 __attribute__((ext_vector_type(2)));

#define B_ 2
#define T_ 2048
#define C_ 512
#define H_ 8
#define FF_ 2048
#define L_ 6
#define V_ 50257
#define M_ (B_*T_)

__device__ __forceinline__ u16 f2b(float f) {
  union { float f; unsigned u; } v; v.f = f;
  unsigned r = v.u + 0x7FFFu + ((v.u >> 16) & 1u);
  return (u16)(r >> 16);
}
__device__ __forceinline__ float b2f(u16 u) {
  union { unsigned u; float f; } v; v.u = ((unsigned)u) << 16; return v.f;
}
__device__ __forceinline__ unsigned pk_bf16(float lo, float hi) {
  unsigned r;
  asm volatile("v_cvt_pk_bf16_f32 %0, %1, %2" : "=v"(r) : "v"(lo), "v"(hi));
  return r;
}
__device__ __forceinline__ float exp2_fast(float x) {
  float r; asm("v_exp_f32 %0, %1" : "=v"(r) : "v"(x)); return r;
}
__device__ __forceinline__ float rcp_fast(float x) {
  float r; asm("v_rcp_f32 %0, %1" : "=v"(r) : "v"(x)); return r;
}

__device__ __forceinline__ void async16(const void* g, void* l) {
  __builtin_amdgcn_global_load_lds((const __attribute__((address_space(1))) unsigned int*)g,
                                   (__attribute__((address_space(3))) unsigned int*)l, 16, 0, 0);
}

template<int N> __device__ __forceinline__ void vwait() {
  if constexpr (N == 0) asm volatile("s_waitcnt vmcnt(0)" ::: "memory");
  else if constexpr (N == 2) asm volatile("s_waitcnt vmcnt(2)" ::: "memory");
  else if constexpr (N == 3) asm volatile("s_waitcnt vmcnt(3)" ::: "memory");
  else if constexpr (N == 4) asm volatile("s_waitcnt vmcnt(4)" ::: "memory");
}

__device__ __forceinline__ bf16x8 scale8(u16x8 v, float s) {
  union { bf16x8 b; unsigned u[4]; } r;
#pragma unroll
  for (int i = 0; i < 4; i++)
    r.u[i] = pk_bf16(b2f(v[2*i]) * s, b2f(v[2*i+1]) * s);
  return r.b;
}

__device__ __forceinline__ float gelu_f(float f) {
  float u = f * f;
  float inner = f * (0.7978845608028654f + 0.03567740814183056f * u);
  inner = fminf(fmaxf(inner, -15.f), 15.f);
  float a = exp2_fast(2.8853900817779268f * inner);
  return f * a * rcp_fast(a + 1.0f);
}

// ---------------- fp32 -> bf16 conversion (all 5 weight tensors, 1 launch) ----
struct CvtArgs { const f32x4* s[5]; u16x4* d[5]; };
__global__ void cvt_all_k(CvtArgs a) {
  const int sizes[5] = { V_*C_/4, L_*3*C_*C_/4, L_*C_*C_/4, L_*FF_*C_/4, L_*C_*FF_/4 };
  int gid = blockIdx.x * blockDim.x + threadIdx.x;
  int stride = gridDim.x * blockDim.x;
#pragma unroll
  for (int seg = 0; seg < 5; seg++) {
    const f32x4* src = a.s[seg];
    u16x4* dst = a.d[seg];
    for (int i = gid; i < sizes[seg]; i += stride) {
      f32x4 v = src[i];
      u16x4 o;
      o[0] = f2b(v[0]); o[1] = f2b(v[1]); o[2] = f2b(v[2]); o[3] = f2b(v[3]);
      dst[i] = o;
    }
  }
}

// ---------------- embedding ----------------
__global__ void embed_k(const int* __restrict__ idx, const float* __restrict__ wte,
                        const float* __restrict__ wpe, float* __restrict__ x) {
  int t = blockIdx.x * 256 + threadIdx.x;
  int row = t >> 7;
  int c4 = t & 127;
  int tok = idx[row];
  int pos = row & (T_ - 1);
  f32x4 a = ((const f32x4*)(wte + (long)tok * C_))[c4];
  f32x4 p = ((const f32x4*)(wpe + (long)pos * C_))[c4];
  ((f32x4*)x)[t] = a + p;
}

// ---------------- layernorm ----------------
__global__ void ln_k(const float* __restrict__ x, const float* __restrict__ w,
                     const float* __restrict__ b, u16* __restrict__ out) {
  int wv = threadIdx.x >> 6;
  int lane = threadIdx.x & 63;
  int row = blockIdx.x * 4 + wv;
  const f32x4* xr = (const f32x4*)(x + (long)row * C_);
  f32x4 v0 = xr[lane * 2], v1 = xr[lane * 2 + 1];
  float s = 0.f, s2 = 0.f;
#pragma unroll
  for (int j = 0; j < 4; j++) { s += v0[j] + v1[j]; s2 += v0[j]*v0[j] + v1[j]*v1[j]; }
#pragma unroll
  for (int off = 32; off >= 1; off >>= 1) { s += __shfl_xor(s, off); s2 += __shfl_xor(s2, off); }
  float mu = s * (1.f / C_);
  float inv = rsqrtf(s2 * (1.f / C_) - mu * mu + 1e-5f);
  const f32x4* wr = (const f32x4*)w;
  const f32x4* br = (const f32x4*)b;
  f32x4 w0 = wr[lane*2], w1 = wr[lane*2+1], b0 = br[lane*2], b1 = br[lane*2+1];
  u16x8 o;
#pragma unroll
  for (int j = 0; j < 4; j++) {
    o[j]     = f2b((v0[j] - mu) * inv * w0[j] + b0[j]);
    o[j + 4] = f2b((v1[j] - mu) * inv * w1[j] + b1[j]);
  }
  *(u16x8*)(out + (long)row * C_ + lane * 8) = o;
}

// ---------------- GEMM: C[M,N] = A[M,K] * B[N,K]^T (BK=32) ----------------
// 3-buffer ring, ONE barrier/iter, stage-before-compute, counted vmcnt.
// EPI: 0 = bf16 store, 2 = gelu(tanh-form)->bf16
template<int EPI, int BM, int BN>
__global__ __launch_bounds__(256) void gemm_bt_k(
    const u16* __restrict__ A, const u16* __restrict__ Bw,
    u16* __restrict__ Cb, float* __restrict__ Cf,
    int N, int K, int ldc)
{
  constexpr int MT = BM / 32;
  constexpr int NT = BN / 32;
  constexpr int AJ = BM / 64;
  constexpr int BJ = BN / 64;
  constexpr int LPT = AJ + BJ;
  __shared__ __align__(16) u16 sA[3][BM * 32];
  __shared__ __align__(16) u16 sB[3][BN * 32];
  const int tid = threadIdx.x;
  const int n0 = blockIdx.x * BN;
  const int m0 = blockIdx.y * BM;
  const int w = tid >> 6;
  const int lane = tid & 63;
  const int wm = (w >> 1) * (BM / 2);
  const int wn = (w & 1) * (BN / 2);
  const int g = lane >> 4;
  const int l15 = lane & 15;
  const int sw3 = l15 & 3;

  f32x4 acc[MT][NT] = {};

  const int nk = K >> 5;
  const int ksw = ((tid & 3) ^ ((tid >> 2) & 3)) * 8;
  const u16* gA[AJ];
  const u16* gB[BJ];
#pragma unroll
  for (int j = 0; j < AJ; j++)
    gA[j] = A + (long)(m0 + (tid >> 2) + j * 64) * K + ksw;
#pragma unroll
  for (int j = 0; j < BJ; j++)
    gB[j] = Bw + (long)(n0 + (tid >> 2) + j * 64) * K + ksw;

  auto stage = [&](int buf, int kt) {
    int ko = kt << 5;
#pragma unroll
    for (int j = 0; j < AJ; j++)
      async16(gA[j] + ko, &sA[buf][(j * 256 + w * 64) * 8]);
#pragma unroll
    for (int j = 0; j < BJ; j++)
      async16(gB[j] + ko, &sB[buf][(j * 256 + w * 64) * 8]);
  };

  stage(0, 0);
  stage(1, 1);
  int cur = 0, nxt = 2;
  for (int kt = 0; kt < nk; kt++) {
    if (kt + 1 < nk) vwait<LPT>(); else vwait<0>();
    __builtin_amdgcn_s_barrier();
    if (kt + 2 < nk) stage(nxt, kt + 2);
    const u16* pa = sA[cur];
    const u16* pb = sB[cur];
    bf16x8 af[MT], bfr[NT];
#pragma unroll
    for (int mt = 0; mt < MT; mt++)
      af[mt] = *(const bf16x8*)(pa + (wm + mt * 16 + l15) * 32 + ((g ^ sw3) * 8));
#pragma unroll
    for (int nt = 0; nt < NT; nt++)
      bfr[nt] = *(const bf16x8*)(pb + (wn + nt * 16 + l15) * 32 + ((g ^ sw3) * 8));
#pragma unroll
    for (int mt = 0; mt < MT; mt++)
#pragma unroll
      for (int nt = 0; nt < NT; nt++)
        acc[mt][nt] = __builtin_amdgcn_mfma_f32_16x16x32_bf16(af[mt], bfr[nt], acc[mt][nt], 0, 0, 0);
    cur = (cur == 2) ? 0 : cur + 1;
    nxt = (nxt == 2) ? 0 : nxt + 1;
  }

#pragma unroll
  for (int mt = 0; mt < MT; mt++) {
    int m = m0 + wm + mt * 16 + g * 4;
#pragma unroll
    for (int nt = 0; nt < NT; nt++) {
      int n = n0 + wn + nt * 16 + l15;
      f32x4 v = acc[mt][nt];
#pragma unroll
      for (int r = 0; r < 4; r++) {
        long ci = (long)(m + r) * ldc + n;
        if (EPI == 0) {
          Cb[ci] = f2b(v[r]);
        } else {
          Cb[ci] = f2b(gelu_f(v[r]));
        }
      }
    }
  }
}

// ---------------- GEMM 64x64, BK=64, fp32 residual-add epilogue ----------------
__global__ __launch_bounds__(256) void gemm_bt64_k(
    const u16* __restrict__ A, const u16* __restrict__ Bw,
    float* __restrict__ Cf, int N, int K, int ldc)
{
  __shared__ __align__(16) u16 sA[3][64 * 64];
  __shared__ __align__(16) u16 sB[3][64 * 64];
  const int tid = threadIdx.x;
  const int n0 = blockIdx.x * 64;
  const int m0 = blockIdx.y * 64;
  const int w = tid >> 6;
  const int lane = tid & 63;
  const int wm = (w >> 1) * 32;
  const int wn = (w & 1) * 32;
  const int g = lane >> 4;
  const int l15 = lane & 15;
  const int sw3 = l15 & 3;

  f32x4 acc[2][2] = {};

  const int nk = K >> 6;
  const int srow = tid >> 3;
  const int sl = tid & 7;
  const int kcol = (((sl & 4) | ((sl & 3) ^ (srow & 3)))) * 8;
  const u16* gA[2];
  const u16* gB[2];
#pragma unroll
  for (int j = 0; j < 2; j++) {
    gA[j] = A + (long)(m0 + srow + j * 32) * K + kcol;
    gB[j] = Bw + (long)(n0 + srow + j * 32) * K + kcol;
  }

  auto stage = [&](int buf, int kt) {
    int ko = kt << 6;
#pragma unroll
    for (int j = 0; j < 2; j++)
      async16(gA[j] + ko, &sA[buf][(j * 256 + w * 64) * 8]);
#pragma unroll
    for (int j = 0; j < 2; j++)
      async16(gB[j] + ko, &sB[buf][(j * 256 + w * 64) * 8]);
  };

  stage(0, 0);
  stage(1, 1);
  int cur = 0, nxt = 2;
  for (int kt = 0; kt < nk; kt++) {
    if (kt + 1 < nk) vwait<4>(); else vwait<0>();
    __builtin_amdgcn_s_barrier();
    if (kt + 2 < nk) stage(nxt, kt + 2);
    const u16* pa = sA[cur];
    const u16* pb = sB[cur];
#pragma unroll
    for (int h = 0; h < 2; h++) {
      bf16x8 af[2], bfr[2];
#pragma unroll
      for (int mt = 0; mt < 2; mt++)
        af[mt] = *(const bf16x8*)(pa + (wm + mt * 16 + l15) * 64 + (((g ^ sw3) + h * 4) * 8));
#pragma unroll
      for (int nt = 0; nt < 2; nt++)
        bfr[nt] = *(const bf16x8*)(pb + (wn + nt * 16 + l15) * 64 + (((g ^ sw3) + h * 4) * 8));
#pragma unroll
      for (int mt = 0; mt < 2; mt++)
#pragma unroll
        for (int nt = 0; nt < 2; nt++)
          acc[mt][nt] = __builtin_amdgcn_mfma_f32_16x16x32_bf16(af[mt], bfr[nt], acc[mt][nt], 0, 0, 0);
    }
    cur = (cur == 2) ? 0 : cur + 1;
    nxt = (nxt == 2) ? 0 : nxt + 1;
  }

#pragma unroll
  for (int mt = 0; mt < 2; mt++) {
    int m = m0 + wm + mt * 16 + g * 4;
#pragma unroll
    for (int nt = 0; nt < 2; nt++) {
      int n = n0 + wn + nt * 16 + l15;
      f32x4 v = acc[mt][nt];
#pragma unroll
      for (int r = 0; r < 4; r++)
        Cf[(long)(m + r) * ldc + n] += v[r];
    }
  }
}

// ---------------- lm_head GEMM: 256x256, 512 threads (8 waves, 64x128/wave) ----
// 3-buf ring LPT=4, grid 3152 = 8*394 XCD-bijective. PLAIN stores (NT stores
// caused 2x write amplification + store stall, R9). 3-bit LDS swizzle:
// slot = g ^ (l15&3) ^ ((l15>>2)&1)  ->  2 lanes per bank-start (free 2-way)
// instead of 4-way with the 2-bit swizzle.
__global__ __launch_bounds__(512) void gemm_lmhead_k(
    const u16* __restrict__ A, const u16* __restrict__ Bw,
    float* __restrict__ Cf, int N)
{
  __shared__ __align__(16) u16 sA[3][256 * 32];
  __shared__ __align__(16) u16 sB[3][256 * 32];
  const int K = 512;
  const int bid = blockIdx.x;
  const int swz = (bid & 7) * 394 + (bid >> 3);
  const int m0 = (swz / 197) * 256;
  const int n0 = (swz % 197) * 256;
  const int tid = threadIdx.x;
  const int w = tid >> 6;
  const int lane = tid & 63;
  const int wm = (w >> 1) * 64;
  const int wn = (w & 1) * 128;
  const int g = lane >> 4;
  const int l15 = lane & 15;
  const int swl = (l15 & 3) ^ ((l15 >> 2) & 1);   // 3-bit-balanced read swizzle

  f32x4 acc[4][8] = {};

  // inverse-swizzled staging source: row = (tid>>2)+j*128 -> row&3=(tid>>2)&3,
  // (row>>2)&1=(tid>>4)&1 for both j (128 even in bit2-shift).
  const int ksw = ((tid & 3) ^ ((tid >> 2) & 3) ^ ((tid >> 4) & 1)) * 8;
  const u16* gA[2];
  const u16* gB[2];
#pragma unroll
  for (int j = 0; j < 2; j++) {
    gA[j] = A + (long)(m0 + (tid >> 2) + j * 128) * K + ksw;
    int brow = n0 + (tid >> 2) + j * 128; if (brow > N - 1) brow = N - 1;
    gB[j] = Bw + (long)brow * K + ksw;
  }

  auto stage = [&](int buf, int kt) {
    int ko = kt << 5;
#pragma unroll
    for (int j = 0; j < 2; j++)
      async16(gA[j] + ko, &sA[buf][(j * 512 + w * 64) * 8]);
#pragma unroll
    for (int j = 0; j < 2; j++)
      async16(gB[j] + ko, &sB[buf][(j * 512 + w * 64) * 8]);
  };

  stage(0, 0);
  stage(1, 1);
  int cur = 0, nxt = 2;
  const int nk = K >> 5;   // 16
  for (int kt = 0; kt < nk; kt++) {
    if (kt + 1 < nk) vwait<4>(); else vwait<0>();
    __builtin_amdgcn_s_barrier();
    if (kt + 2 < nk) stage(nxt, kt + 2);
    const u16* pa = sA[cur];
    const u16* pb = sB[cur];
    bf16x8 af[4], bfr[8];
#pragma unroll
    for (int mt = 0; mt < 4; mt++)
      af[mt] = *(const bf16x8*)(pa + (wm + mt * 16 + l15) * 32 + ((g ^ swl) * 8));
#pragma unroll
    for (int nt = 0; nt < 8; nt++)
      bfr[nt] = *(const bf16x8*)(pb + (wn + nt * 16 + l15) * 32 + ((g ^ swl) * 8));
    __builtin_amdgcn_s_setprio(1);
#pragma unroll
    for (int mt = 0; mt < 4; mt++)
#pragma unroll
      for (int nt = 0; nt < 8; nt++)
        acc[mt][nt] = __builtin_amdgcn_mfma_f32_16x16x32_bf16(af[mt], bfr[nt], acc[mt][nt], 0, 0, 0);
    __builtin_amdgcn_s_setprio(0);
    cur = (cur == 2) ? 0 : cur + 1;
    nxt = (nxt == 2) ? 0 : nxt + 1;
  }

#pragma unroll
  for (int mt = 0; mt < 4; mt++) {
    int m = m0 + wm + mt * 16 + g * 4;
#pragma unroll
    for (int nt = 0; nt < 8; nt++) {
      int n = n0 + wn + nt * 16 + l15;
      f32x4 v = acc[mt][nt];
      if (n < N) {
#pragma unroll
        for (int r = 0; r < 4; r++)
          Cf[(long)(m + r) * N + n] = v[r];
      }
    }
  }
}

// ---------------- flash attention: 4 waves / 64-row qblk ----------------
__global__ __launch_bounds__(256) void attn_k(const u16* __restrict__ qkv, u16* __restrict__ out) {
  const int bh = blockIdx.y;
  const int b = bh >> 3;
  const int h = bh & 7;
  const int tid = threadIdx.x;
  const int wv = tid >> 6;
  const int lane = tid & 63;
  const int g = lane >> 4;
  const int l15 = lane & 15;
  const int qblk = 31 - blockIdx.x;

  __shared__ __align__(16) u16 Ks[2][64 * 64];
  __shared__ __align__(16) u16 Vt[2][64 * 72];
  __shared__ __align__(16) u16 Ps[4][16 * 64];

  const long base = (long)b * T_ * 1536;
  const u16* kbase = qkv + base + 512 + h * 64;
  const u16* vbase = qkv + base + 1024 + h * 64;
  const int kq = tid & 15;
  const int dg = (tid >> 4) & 7;
  const float qscale = 0.18033688011112042f;  // 1/sqrt(64) * log2(e)

  const int q0 = qblk * 64 + wv * 16;

  const u16* qrow = qkv + base + (long)(q0 + l15) * 1536 + h * 64;
  bf16x8 qf0 = scale8(*(const u16x8*)(qrow + g * 8), qscale);
  bf16x8 qf1 = scale8(*(const u16x8*)(qrow + 32 + g * 8), qscale);

  f32x4 o[4] = {};
  float mrun[4] = {-1e30f, -1e30f, -1e30f, -1e30f};
  float lrun[4] = {0.f, 0.f, 0.f, 0.f};
  const int kvend = qblk * 64 + 64;

  u16x8 vreg[4];
#pragma unroll
  for (int i = 0; i < 2; i++) {
    int chunk = i * 256 + tid;
    int row = chunk >> 3, c8 = chunk & 7;
    async16(kbase + (long)row * 1536 + (c8 ^ (row & 7)) * 8,
            &Ks[0][(i * 256 + wv * 64) * 8]);
  }
  if (tid < 128) {
#pragma unroll
    for (int t = 0; t < 4; t++)
      vreg[t] = *(const u16x8*)(vbase + (long)(kq + 16 * t) * 1536 + dg * 8);
#pragma unroll
    for (int e = 0; e < 8; e++) {
      int d = dg * 8 + e;
      u32x2 wq = { (unsigned)vreg[0][e] | ((unsigned)vreg[1][e] << 16),
                   (unsigned)vreg[2][e] | ((unsigned)vreg[3][e] << 16) };
      *(u32x2*)(&Vt[0][d * 72 + kq * 4]) = wq;
    }
  }
  __syncthreads();

  int cur = 0;
  for (int j0 = 0; j0 < kvend; j0 += 64, cur ^= 1) {
    const bool more = (j0 + 64) < kvend;
    if (more) {
      int jn = j0 + 64;
#pragma unroll
      for (int i = 0; i < 2; i++) {
        int chunk = i * 256 + tid;
        int row = chunk >> 3, c8 = chunk & 7;
        async16(kbase + (long)(jn + row) * 1536 + (c8 ^ (row & 7)) * 8,
                &Ks[cur ^ 1][(i * 256 + wv * 64) * 8]);
      }
      if (tid < 128) {
#pragma unroll
        for (int t = 0; t < 4; t++)
          vreg[t] = *(const u16x8*)(vbase + (long)(jn + kq + 16 * t) * 1536 + dg * 8);
      }
    }

    f32x4 s[4] = {};
    const u16* kp = Ks[cur];
#pragma unroll
    for (int t = 0; t < 4; t++) {
      int row = t * 16 + l15;
      const u16* kr = kp + row * 64;
      bf16x8 k0 = *(const bf16x8*)(kr + ((g ^ (row & 7)) * 8));
      bf16x8 k1 = *(const bf16x8*)(kr + (((4 + g) ^ (row & 7)) * 8));
      s[t] = __builtin_amdgcn_mfma_f32_16x16x32_bf16(qf0, k0, s[t], 0, 0, 0);
      s[t] = __builtin_amdgcn_mfma_f32_16x16x32_bf16(qf1, k1, s[t], 0, 0, 0);
    }

    const bool diag = (j0 + 64) == kvend;
    u16* pw = Ps[wv];
#pragma unroll
    for (int r = 0; r < 4; r++) {
      int row = q0 + g * 4 + r;
      float v0 = s[0][r], v1 = s[1][r], v2 = s[2][r], v3 = s[3][r];
      if (diag) {
        if (j0 +      l15 > row) v0 = -1e30f;
        if (j0 + 16 + l15 > row) v1 = -1e30f;
        if (j0 + 32 + l15 > row) v2 = -1e30f;
        if (j0 + 48 + l15 > row) v3 = -1e30f;
      }
      float mloc = fmaxf(fmaxf(v0, v1), fmaxf(v2, v3));
      float m = mrun[r];
      if (!__all(mloc <= m + 8.0f)) {
        float mx = mloc;
        mx = fmaxf(mx, __shfl_xor(mx, 1));
        mx = fmaxf(mx, __shfl_xor(mx, 2));
        mx = fmaxf(mx, __shfl_xor(mx, 4));
        mx = fmaxf(mx, __shfl_xor(mx, 8));
        float mn = fmaxf(m, mx);
        float sc2 = exp2_fast(m - mn);
        lrun[r] *= sc2;
#pragma unroll
        for (int dt = 0; dt < 4; dt++) o[dt][r] *= sc2;
        m = mn; mrun[r] = mn;
      }
      float e0 = exp2_fast(v0 - m), e1 = exp2_fast(v1 - m);
      float e2 = exp2_fast(v2 - m), e3 = exp2_fast(v3 - m);
      lrun[r] += (e0 + e1) + (e2 + e3);
      u32x2 pkq = { pk_bf16(e0, e1), pk_bf16(e2, e3) };
      int prow = g * 4 + r;
      int byt = prow * 128 + ((((l15 >> 1) ^ (prow & 7)) << 4)) + (l15 & 1) * 8;
      *(u32x2*)((char*)pw + byt) = pkq;
    }

    const u16* vt = Vt[cur];
    bf16x8 pf0 = *(const bf16x8*)((char*)pw + l15 * 128 + (((g) ^ (l15 & 7)) << 4));
    bf16x8 pf1 = *(const bf16x8*)((char*)pw + l15 * 128 + (((4 + g) ^ (l15 & 7)) << 4));
#pragma unroll
    for (int dt = 0; dt < 4; dt++) {
      int d = dt * 16 + l15;
      bf16x8 vf0 = *(const bf16x8*)(vt + d * 72 + g * 8);
      bf16x8 vf1 = *(const bf16x8*)(vt + d * 72 + 32 + g * 8);
      o[dt] = __builtin_amdgcn_mfma_f32_16x16x32_bf16(pf0, vf0, o[dt], 0, 0, 0);
      o[dt] = __builtin_amdgcn_mfma_f32_16x16x32_bf16(pf1, vf1, o[dt], 0, 0, 0);
    }

    if (more && tid < 128) {
#pragma unroll
      for (int e = 0; e < 8; e++) {
        int d = dg * 8 + e;
        u32x2 wq = { (unsigned)vreg[0][e] | ((unsigned)vreg[1][e] << 16),
                     (unsigned)vreg[2][e] | ((unsigned)vreg[3][e] << 16) };
        *(u32x2*)(&Vt[cur ^ 1][d * 72 + kq * 4]) = wq;
      }
    }
    __syncthreads();
  }

#pragma unroll
  for (int r = 0; r < 4; r++) {
    float ls = lrun[r];
    ls += __shfl_xor(ls, 1); ls += __shfl_xor(ls, 2);
    ls += __shfl_xor(ls, 4); ls += __shfl_xor(ls, 8);
    float inv = 1.0f / ls;
    int row = q0 + g * 4 + r;
    u16* orow = out + (long)(b * T_ + row) * C_ + h * 64;
#pragma unroll
    for (int dt = 0; dt < 4; dt++)
      orow[dt * 16 + l15] = f2b(o[dt][r] * inv);
  }
}

// ---------------- host launcher ----------------
extern "C" void kernel_launch(void* const* d_in, const int* in_sizes, int n_in,
                              void* d_out, int out_size, void* d_ws, size_t ws_size,
                              hipStream_t stream) {
  const int*   idx    = (const int*)  d_in[0];
  const float* wte    = (const float*)d_in[1];
  const float* wpe    = (const float*)d_in[2];
  const float* ln1w   = (const float*)d_in[3];
  const float* ln1b   = (const float*)d_in[4];
  const float* wattn  = (const float*)d_in[5];
  const float* wcproj = (const float*)d_in[6];
  const float* ln2w   = (const float*)d_in[7];
  const float* ln2b   = (const float*)d_in[8];
  const float* wfc    = (const float*)d_in[9];
  const float* wproj2 = (const float*)d_in[10];
  const float* lnfw   = (const float*)d_in[11];
  const float* lnfb   = (const float*)d_in[12];
  float* out = (float*)d_out;

  char* p = (char*)d_ws;
  size_t off = 0;
  auto alloc = [&](size_t bytes) -> void* {
    void* r = p + off; off += (bytes + 255) & ~(size_t)255; return r;
  };
  float* x    = (float*)alloc((size_t)M_ * C_ * 4);
  u16* xn     = (u16*)alloc((size_t)M_ * C_ * 2);
  u16* qkvb   = (u16*)alloc((size_t)M_ * 3 * C_ * 2);
  u16* attb   = (u16*)alloc((size_t)M_ * C_ * 2);
  u16* hb     = (u16*)alloc((size_t)M_ * FF_ * 2);
  u16* wteB   = (u16*)alloc((size_t)V_ * C_ * 2);
  u16* wattnB = (u16*)alloc((size_t)L_ * 3 * C_ * C_ * 2);
  u16* wprojB = (u16*)alloc((size_t)L_ * C_ * C_ * 2);
  u16* wfcB   = (u16*)alloc((size_t)L_ * FF_ * C_ * 2);
  u16* wp2B   = (u16*)alloc((size_t)L_ * C_ * FF_ * 2);
  if (off > ws_size) return;

  CvtArgs ca;
  ca.s[0] = (const f32x4*)wte;    ca.d[0] = (u16x4*)wteB;
  ca.s[1] = (const f32x4*)wattn;  ca.d[1] = (u16x4*)wattnB;
  ca.s[2] = (const f32x4*)wcproj; ca.d[2] = (u16x4*)wprojB;
  ca.s[3] = (const f32x4*)wfc;    ca.d[3] = (u16x4*)wfcB;
  ca.s[4] = (const f32x4*)wproj2; ca.d[4] = (u16x4*)wp2B;
  cvt_all_k<<<dim3(2048), dim3(256), 0, stream>>>(ca);

  embed_k<<<dim3(M_ * C_ / 4 / 256), dim3(256), 0, stream>>>(idx, wte, wpe, x);

  for (int l = 0; l < L_; l++) {
    ln_k<<<dim3(M_ / 4), dim3(256), 0, stream>>>(x, ln1w + l * C_, ln1b + l * C_, xn);
    gemm_bt_k<0, 64, 128><<<dim3(12, 64), dim3(256), 0, stream>>>(
        xn, wattnB + (size_t)l * 3 * C_ * C_, qkvb, nullptr, 3 * C_, C_, 3 * C_);
    attn_k<<<dim3(32, B_ * H_), dim3(256), 0, stream>>>(qkvb, attb);
    gemm_bt64_k<<<dim3(8, 64), dim3(256), 0, stream>>>(
        attb, wprojB + (size_t)l * C_ * C_, x, C_, C_, C_);
    ln_k<<<dim3(M_ / 4), dim3(256), 0, stream>>>(x, ln2w + l * C_, ln2b + l * C_, xn);
    gemm_bt_k<2, 128, 128><<<dim3(16, 32), dim3(256), 0, stream>>>(
        xn, wfcB + (size_t)l * FF_ * C_, hb, nullptr, FF_, C_, FF_);
    gemm_bt64_k<<<dim3(8, 64), dim3(256), 0, stream>>>(
        hb, wp2B + (size_t)l * C_ * FF_, x, C_, FF_, C_);
  }
  ln_k<<<dim3(M_ / 4), dim3(256), 0, stream>>>(x, lnfw, lnfb, xn);
  gemm_lmhead_k<<<dim3(16 * 197), dim3(512), 0, stream>>>(xn, wteB, out, V_);
}

// Round 11
// 1218.686 us; speedup vs baseline: 1.3327x; 1.0323x over previous
//
#include <hip/hip_runtime.h>

typedef unsigned short u16;
typedef short bf16x8 __attribute__((ext_vector_type(8)));
typedef float f32x4 __attribute__((ext_vector_type(4)));
typedef unsigned short u16x4 __attribute__((ext_vector_type(4)));
typedef unsigned short u16x8 __attribute__((ext_vector_type(8)));
typedef unsigned int u32x2 __attribute__((ext_vector_type(2)));

#define B_ 2
#define T_ 2048
#define C_ 512
#define H_ 8
#define FF_ 2048
#define L_ 6
#define V_ 50257
#define M_ (B_*T_)

__device__ __forceinline__ u16 f2b(float f) {
  union { float f; unsigned u; } v; v.f = f;
  unsigned r = v.u + 0x7FFFu + ((v.u >> 16) & 1u);
  return (u16)(r >> 16);
}
__device__ __forceinline__ float b2f(u16 u) {
  union { unsigned u; float f; } v; v.u = ((unsigned)u) << 16; return v.f;
}
__device__ __forceinline__ unsigned pk_bf16(float lo, float hi) {
  unsigned r;
  asm volatile("v_cvt_pk_bf16_f32 %0, %1, %2" : "=v"(r) : "v"(lo), "v"(hi));
  return r;
}
__device__ __forceinline__ float exp2_fast(float x) {
  float r; asm("v_exp_f32 %0, %1" : "=v"(r) : "v"(x)); return r;
}
__device__ __forceinline__ float rcp_fast(float x) {
  float r; asm("v_rcp_f32 %0, %1" : "=v"(r) : "v"(x)); return r;
}

__device__ __forceinline__ void async16(const void* g, void* l) {
  __builtin_amdgcn_global_load_lds((const __attribute__((address_space(1))) unsigned int*)g,
                                   (__attribute__((address_space(3))) unsigned int*)l, 16, 0, 0);
}

template<int N> __device__ __forceinline__ void vwait() {
  if constexpr (N == 0) asm volatile("s_waitcnt vmcnt(0)" ::: "memory");
  else if constexpr (N == 2) asm volatile("s_waitcnt vmcnt(2)" ::: "memory");
  else if constexpr (N == 3) asm volatile("s_waitcnt vmcnt(3)" ::: "memory");
  else if constexpr (N == 4) asm volatile("s_waitcnt vmcnt(4)" ::: "memory");
}

__device__ __forceinline__ bf16x8 scale8(u16x8 v, float s) {
  union { bf16x8 b; unsigned u[4]; } r;
#pragma unroll
  for (int i = 0; i < 4; i++)
    r.u[i] = pk_bf16(b2f(v[2*i]) * s, b2f(v[2*i+1]) * s);
  return r.b;
}

__device__ __forceinline__ float gelu_f(float f) {
  float u = f * f;
  float inner = f * (0.7978845608028654f + 0.03567740814183056f * u);
  inner = fminf(fmaxf(inner, -15.f), 15.f);
  float a = exp2_fast(2.8853900817779268f * inner);
  return f * a * rcp_fast(a + 1.0f);
}

// ---------------- fp32 -> bf16 conversion (all 5 weight tensors, 1 launch) ----
struct CvtArgs { const f32x4* s[5]; u16x4* d[5]; };
__global__ void cvt_all_k(CvtArgs a) {
  const int sizes[5] = { V_*C_/4, L_*3*C_*C_/4, L_*C_*C_/4, L_*FF_*C_/4, L_*C_*FF_/4 };
  int gid = blockIdx.x * blockDim.x + threadIdx.x;
  int stride = gridDim.x * blockDim.x;
#pragma unroll
  for (int seg = 0; seg < 5; seg++) {
    const f32x4* src = a.s[seg];
    u16x4* dst = a.d[seg];
    for (int i = gid; i < sizes[seg]; i += stride) {
      f32x4 v = src[i];
      u16x4 o;
      o[0] = f2b(v[0]); o[1] = f2b(v[1]); o[2] = f2b(v[2]); o[3] = f2b(v[3]);
      dst[i] = o;
    }
  }
}

// ---------------- embedding ----------------
__global__ void embed_k(const int* __restrict__ idx, const float* __restrict__ wte,
                        const float* __restrict__ wpe, float* __restrict__ x) {
  int t = blockIdx.x * 256 + threadIdx.x;
  int row = t >> 7;
  int c4 = t & 127;
  int tok = idx[row];
  int pos = row & (T_ - 1);
  f32x4 a = ((const f32x4*)(wte + (long)tok * C_))[c4];
  f32x4 p = ((const f32x4*)(wpe + (long)pos * C_))[c4];
  ((f32x4*)x)[t] = a + p;
}

// ---------------- layernorm ----------------
__global__ void ln_k(const float* __restrict__ x, const float* __restrict__ w,
                     const float* __restrict__ b, u16* __restrict__ out) {
  int wv = threadIdx.x >> 6;
  int lane = threadIdx.x & 63;
  int row = blockIdx.x * 4 + wv;
  const f32x4* xr = (const f32x4*)(x + (long)row * C_);
  f32x4 v0 = xr[lane * 2], v1 = xr[lane * 2 + 1];
  float s = 0.f, s2 = 0.f;
#pragma unroll
  for (int j = 0; j < 4; j++) { s += v0[j] + v1[j]; s2 += v0[j]*v0[j] + v1[j]*v1[j]; }
#pragma unroll
  for (int off = 32; off >= 1; off >>= 1) { s += __shfl_xor(s, off); s2 += __shfl_xor(s2, off); }
  float mu = s * (1.f / C_);
  float inv = rsqrtf(s2 * (1.f / C_) - mu * mu + 1e-5f);
  const f32x4* wr = (const f32x4*)w;
  const f32x4* br = (const f32x4*)b;
  f32x4 w0 = wr[lane*2], w1 = wr[lane*2+1], b0 = br[lane*2], b1 = br[lane*2+1];
  u16x8 o;
#pragma unroll
  for (int j = 0; j < 4; j++) {
    o[j]     = f2b((v0[j] - mu) * inv * w0[j] + b0[j]);
    o[j + 4] = f2b((v1[j] - mu) * inv * w1[j] + b1[j]);
  }
  *(u16x8*)(out + (long)row * C_ + lane * 8) = o;
}

// ---------------- GEMM: C[M,N] = A[M,K] * B[N,K]^T (BK=32) ----------------
// 3-buffer ring, ONE barrier/iter, stage-before-compute, counted vmcnt.
// 1D grid, XCD-bijective m-slice mapping: XCD c owns m-tiles [c*MX, (c+1)*MX),
// all n; within-XCD order m-fastest -> per-XCD L2 working set = A-slice + B.
// EPI: 0 = bf16 store, 2 = gelu(tanh-form)->bf16
template<int EPI, int BM, int BN>
__global__ __launch_bounds__(256) void gemm_bt_k(
    const u16* __restrict__ A, const u16* __restrict__ Bw,
    u16* __restrict__ Cb, float* __restrict__ Cf,
    int N, int K, int ldc)
{
  constexpr int MT = BM / 32;
  constexpr int NT = BN / 32;
  constexpr int AJ = BM / 64;
  constexpr int BJ = BN / 64;
  constexpr int LPT = AJ + BJ;
  constexpr int MX = (M_ / BM) / 8;   // m-tiles per XCD
  __shared__ __align__(16) u16 sA[3][BM * 32];
  __shared__ __align__(16) u16 sB[3][BN * 32];
  const int bid = blockIdx.x;
  const int xc = bid & 7;
  const int jj = bid >> 3;
  const int m0 = (xc * MX + (jj % MX)) * BM;
  const int n0 = (jj / MX) * BN;
  const int tid = threadIdx.x;
  const int w = tid >> 6;
  const int lane = tid & 63;
  const int wm = (w >> 1) * (BM / 2);
  const int wn = (w & 1) * (BN / 2);
  const int g = lane >> 4;
  const int l15 = lane & 15;
  const int sw3 = l15 & 3;

  f32x4 acc[MT][NT] = {};

  const int nk = K >> 5;
  const int ksw = ((tid & 3) ^ ((tid >> 2) & 3)) * 8;
  const u16* gA[AJ];
  const u16* gB[BJ];
#pragma unroll
  for (int j = 0; j < AJ; j++)
    gA[j] = A + (long)(m0 + (tid >> 2) + j * 64) * K + ksw;
#pragma unroll
  for (int j = 0; j < BJ; j++)
    gB[j] = Bw + (long)(n0 + (tid >> 2) + j * 64) * K + ksw;

  auto stage = [&](int buf, int kt) {
    int ko = kt << 5;
#pragma unroll
    for (int j = 0; j < AJ; j++)
      async16(gA[j] + ko, &sA[buf][(j * 256 + w * 64) * 8]);
#pragma unroll
    for (int j = 0; j < BJ; j++)
      async16(gB[j] + ko, &sB[buf][(j * 256 + w * 64) * 8]);
  };

  stage(0, 0);
  stage(1, 1);
  int cur = 0, nxt = 2;
  for (int kt = 0; kt < nk; kt++) {
    if (kt + 1 < nk) vwait<LPT>(); else vwait<0>();
    __builtin_amdgcn_s_barrier();
    if (kt + 2 < nk) stage(nxt, kt + 2);
    const u16* pa = sA[cur];
    const u16* pb = sB[cur];
    bf16x8 af[MT], bfr[NT];
#pragma unroll
    for (int mt = 0; mt < MT; mt++)
      af[mt] = *(const bf16x8*)(pa + (wm + mt * 16 + l15) * 32 + ((g ^ sw3) * 8));
#pragma unroll
    for (int nt = 0; nt < NT; nt++)
      bfr[nt] = *(const bf16x8*)(pb + (wn + nt * 16 + l15) * 32 + ((g ^ sw3) * 8));
#pragma unroll
    for (int mt = 0; mt < MT; mt++)
#pragma unroll
      for (int nt = 0; nt < NT; nt++)
        acc[mt][nt] = __builtin_amdgcn_mfma_f32_16x16x32_bf16(af[mt], bfr[nt], acc[mt][nt], 0, 0, 0);
    cur = (cur == 2) ? 0 : cur + 1;
    nxt = (nxt == 2) ? 0 : nxt + 1;
  }

#pragma unroll
  for (int mt = 0; mt < MT; mt++) {
    int m = m0 + wm + mt * 16 + g * 4;
#pragma unroll
    for (int nt = 0; nt < NT; nt++) {
      int n = n0 + wn + nt * 16 + l15;
      f32x4 v = acc[mt][nt];
#pragma unroll
      for (int r = 0; r < 4; r++) {
        long ci = (long)(m + r) * ldc + n;
        if (EPI == 0) {
          Cb[ci] = f2b(v[r]);
        } else {
          Cb[ci] = f2b(gelu_f(v[r]));
        }
      }
    }
  }
}

// ---------------- GEMM 64x64, BK=64, fp32 residual-add epilogue ----------------
// Same XCD m-slice mapping (MX=8).
__global__ __launch_bounds__(256) void gemm_bt64_k(
    const u16* __restrict__ A, const u16* __restrict__ Bw,
    float* __restrict__ Cf, int N, int K, int ldc)
{
  __shared__ __align__(16) u16 sA[3][64 * 64];
  __shared__ __align__(16) u16 sB[3][64 * 64];
  const int bid = blockIdx.x;
  const int xc = bid & 7;
  const int jj = bid >> 3;
  const int m0 = (xc * 8 + (jj & 7)) * 64;
  const int n0 = (jj >> 3) * 64;
  const int tid = threadIdx.x;
  const int w = tid >> 6;
  const int lane = tid & 63;
  const int wm = (w >> 1) * 32;
  const int wn = (w & 1) * 32;
  const int g = lane >> 4;
  const int l15 = lane & 15;
  const int sw3 = l15 & 3;

  f32x4 acc[2][2] = {};

  const int nk = K >> 6;
  const int srow = tid >> 3;
  const int sl = tid & 7;
  const int kcol = (((sl & 4) | ((sl & 3) ^ (srow & 3)))) * 8;
  const u16* gA[2];
  const u16* gB[2];
#pragma unroll
  for (int j = 0; j < 2; j++) {
    gA[j] = A + (long)(m0 + srow + j * 32) * K + kcol;
    gB[j] = Bw + (long)(n0 + srow + j * 32) * K + kcol;
  }

  auto stage = [&](int buf, int kt) {
    int ko = kt << 6;
#pragma unroll
    for (int j = 0; j < 2; j++)
      async16(gA[j] + ko, &sA[buf][(j * 256 + w * 64) * 8]);
#pragma unroll
    for (int j = 0; j < 2; j++)
      async16(gB[j] + ko, &sB[buf][(j * 256 + w * 64) * 8]);
  };

  stage(0, 0);
  stage(1, 1);
  int cur = 0, nxt = 2;
  for (int kt = 0; kt < nk; kt++) {
    if (kt + 1 < nk) vwait<4>(); else vwait<0>();
    __builtin_amdgcn_s_barrier();
    if (kt + 2 < nk) stage(nxt, kt + 2);
    const u16* pa = sA[cur];
    const u16* pb = sB[cur];
#pragma unroll
    for (int h = 0; h < 2; h++) {
      bf16x8 af[2], bfr[2];
#pragma unroll
      for (int mt = 0; mt < 2; mt++)
        af[mt] = *(const bf16x8*)(pa + (wm + mt * 16 + l15) * 64 + (((g ^ sw3) + h * 4) * 8));
#pragma unroll
      for (int nt = 0; nt < 2; nt++)
        bfr[nt] = *(const bf16x8*)(pb + (wn + nt * 16 + l15) * 64 + (((g ^ sw3) + h * 4) * 8));
#pragma unroll
      for (int mt = 0; mt < 2; mt++)
#pragma unroll
        for (int nt = 0; nt < 2; nt++)
          acc[mt][nt] = __builtin_amdgcn_mfma_f32_16x16x32_bf16(af[mt], bfr[nt], acc[mt][nt], 0, 0, 0);
    }
    cur = (cur == 2) ? 0 : cur + 1;
    nxt = (nxt == 2) ? 0 : nxt + 1;
  }

#pragma unroll
  for (int mt = 0; mt < 2; mt++) {
    int m = m0 + wm + mt * 16 + g * 4;
#pragma unroll
    for (int nt = 0; nt < 2; nt++) {
      int n = n0 + wn + nt * 16 + l15;
      f32x4 v = acc[mt][nt];
#pragma unroll
      for (int r = 0; r < 4; r++)
        Cf[(long)(m + r) * ldc + n] += v[r];
    }
  }
}

// ---------------- lm_head GEMM: 256x128, 512 threads (8 waves, 64x64/wave) ----
// 3-buf single-barrier ring LPT=3, LDS 72KB -> 2 blocks/CU (epilogue store
// drain overlaps the co-resident block's K-loop). XCD c owns m-tiles 2c,2c+1
// (A-slice 0.5MB L2-hot), n fastest. Plain stores (NT = 2x write amp, R9).
__global__ __launch_bounds__(512) void gemm_lmhead_k(
    const u16* __restrict__ A, const u16* __restrict__ Bw,
    float* __restrict__ Cf, int N)
{
  __shared__ __align__(16) u16 sA[3][256 * 32];
  __shared__ __align__(16) u16 sB[3][128 * 32];
  const int K = 512;
  const int bid = blockIdx.x;           // 6288 = 8 * 786, 786 = 2*393
  const int xc = bid & 7;
  const int j = bid >> 3;
  const int half = (j >= 393);
  const int jn = half ? j - 393 : j;
  const int m0 = (xc * 2 + half) * 256;
  const int n0 = jn * 128;
  const int tid = threadIdx.x;
  const int w = tid >> 6;
  const int lane = tid & 63;
  const int wm = (w >> 1) * 64;
  const int wn = (w & 1) * 64;
  const int g = lane >> 4;
  const int l15 = lane & 15;
  const int swl = (l15 & 3) ^ ((l15 >> 2) & 1);

  f32x4 acc[4][4] = {};

  const int ksw = ((tid & 3) ^ ((tid >> 2) & 3) ^ ((tid >> 4) & 1)) * 8;
  const u16* gA[2];
#pragma unroll
  for (int jA = 0; jA < 2; jA++)
    gA[jA] = A + (long)(m0 + (tid >> 2) + jA * 128) * K + ksw;
  int brow = n0 + (tid >> 2); if (brow > N - 1) brow = N - 1;
  const u16* gB0 = Bw + (long)brow * K + ksw;

  auto stage = [&](int buf, int kt) {
    int ko = kt << 5;
#pragma unroll
    for (int jA = 0; jA < 2; jA++)
      async16(gA[jA] + ko, &sA[buf][(jA * 512 + w * 64) * 8]);
    async16(gB0 + ko, &sB[buf][(w * 64) * 8]);
  };

  stage(0, 0);
  stage(1, 1);
  int cur = 0, nxt = 2;
  const int nk = K >> 5;   // 16
  for (int kt = 0; kt < nk; kt++) {
    if (kt + 1 < nk) vwait<3>(); else vwait<0>();
    __builtin_amdgcn_s_barrier();
    if (kt + 2 < nk) stage(nxt, kt + 2);
    const u16* pa = sA[cur];
    const u16* pb = sB[cur];
    bf16x8 af[4], bfr[4];
#pragma unroll
    for (int mt = 0; mt < 4; mt++)
      af[mt] = *(const bf16x8*)(pa + (wm + mt * 16 + l15) * 32 + ((g ^ swl) * 8));
#pragma unroll
    for (int nt = 0; nt < 4; nt++)
      bfr[nt] = *(const bf16x8*)(pb + (wn + nt * 16 + l15) * 32 + ((g ^ swl) * 8));
    __builtin_amdgcn_s_setprio(1);
#pragma unroll
    for (int mt = 0; mt < 4; mt++)
#pragma unroll
      for (int nt = 0; nt < 4; nt++)
        acc[mt][nt] = __builtin_amdgcn_mfma_f32_16x16x32_bf16(af[mt], bfr[nt], acc[mt][nt], 0, 0, 0);
    __builtin_amdgcn_s_setprio(0);
    cur = (cur == 2) ? 0 : cur + 1;
    nxt = (nxt == 2) ? 0 : nxt + 1;
  }

#pragma unroll
  for (int mt = 0; mt < 4; mt++) {
    int m = m0 + wm + mt * 16 + g * 4;
#pragma unroll
    for (int nt = 0; nt < 4; nt++) {
      int n = n0 + wn + nt * 16 + l15;
      f32x4 v = acc[mt][nt];
      if (n < N) {
#pragma unroll
        for (int r = 0; r < 4; r++)
          Cf[(long)(m + r) * N + n] = v[r];
      }
    }
  }
}

// ---------------- flash attention: 4 waves / 64-row qblk ----------------
__global__ __launch_bounds__(256) void attn_k(const u16* __restrict__ qkv, u16* __restrict__ out) {
  const int bh = blockIdx.y;
  const int b = bh >> 3;
  const int h = bh & 7;
  const int tid = threadIdx.x;
  const int wv = tid >> 6;
  const int lane = tid & 63;
  const int g = lane >> 4;
  const int l15 = lane & 15;
  const int qblk = 31 - blockIdx.x;

  __shared__ __align__(16) u16 Ks[2][64 * 64];
  __shared__ __align__(16) u16 Vt[2][64 * 72];
  __shared__ __align__(16) u16 Ps[4][16 * 64];

  const long base = (long)b * T_ * 1536;
  const u16* kbase = qkv + base + 512 + h * 64;
  const u16* vbase = qkv + base + 1024 + h * 64;
  const int kq = tid & 15;
  const int dg = (tid >> 4) & 7;
  const float qscale = 0.18033688011112042f;  // 1/sqrt(64) * log2(e)

  const int q0 = qblk * 64 + wv * 16;

  const u16* qrow = qkv + base + (long)(q0 + l15) * 1536 + h * 64;
  bf16x8 qf0 = scale8(*(const u16x8*)(qrow + g * 8), qscale);
  bf16x8 qf1 = scale8(*(const u16x8*)(qrow + 32 + g * 8), qscale);

  f32x4 o[4] = {};
  float mrun[4] = {-1e30f, -1e30f, -1e30f, -1e30f};
  float lrun[4] = {0.f, 0.f, 0.f, 0.f};
  const int kvend = qblk * 64 + 64;

  u16x8 vreg[4];
#pragma unroll
  for (int i = 0; i < 2; i++) {
    int chunk = i * 256 + tid;
    int row = chunk >> 3, c8 = chunk & 7;
    async16(kbase + (long)row * 1536 + (c8 ^ (row & 7)) * 8,
            &Ks[0][(i * 256 + wv * 64) * 8]);
  }
  if (tid < 128) {
#pragma unroll
    for (int t = 0; t < 4; t++)
      vreg[t] = *(const u16x8*)(vbase + (long)(kq + 16 * t) * 1536 + dg * 8);
#pragma unroll
    for (int e = 0; e < 8; e++) {
      int d = dg * 8 + e;
      u32x2 wq = { (unsigned)vreg[0][e] | ((unsigned)vreg[1][e] << 16),
                   (unsigned)vreg[2][e] | ((unsigned)vreg[3][e] << 16) };
      *(u32x2*)(&Vt[0][d * 72 + kq * 4]) = wq;
    }
  }
  __syncthreads();

  int cur = 0;
  for (int j0 = 0; j0 < kvend; j0 += 64, cur ^= 1) {
    const bool more = (j0 + 64) < kvend;
    if (more) {
      int jn = j0 + 64;
#pragma unroll
      for (int i = 0; i < 2; i++) {
        int chunk = i * 256 + tid;
        int row = chunk >> 3, c8 = chunk & 7;
        async16(kbase + (long)(jn + row) * 1536 + (c8 ^ (row & 7)) * 8,
                &Ks[cur ^ 1][(i * 256 + wv * 64) * 8]);
      }
      if (tid < 128) {
#pragma unroll
        for (int t = 0; t < 4; t++)
          vreg[t] = *(const u16x8*)(vbase + (long)(jn + kq + 16 * t) * 1536 + dg * 8);
      }
    }

    f32x4 s[4] = {};
    const u16* kp = Ks[cur];
#pragma unroll
    for (int t = 0; t < 4; t++) {
      int row = t * 16 + l15;
      const u16* kr = kp + row * 64;
      bf16x8 k0 = *(const bf16x8*)(kr + ((g ^ (row & 7)) * 8));
      bf16x8 k1 = *(const bf16x8*)(kr + (((4 + g) ^ (row & 7)) * 8));
      s[t] = __builtin_amdgcn_mfma_f32_16x16x32_bf16(qf0, k0, s[t], 0, 0, 0);
      s[t] = __builtin_amdgcn_mfma_f32_16x16x32_bf16(qf1, k1, s[t], 0, 0, 0);
    }

    const bool diag = (j0 + 64) == kvend;
    u16* pw = Ps[wv];
#pragma unroll
    for (int r = 0; r < 4; r++) {
      int row = q0 + g * 4 + r;
      float v0 = s[0][r], v1 = s[1][r], v2 = s[2][r], v3 = s[3][r];
      if (diag) {
        if (j0 +      l15 > row) v0 = -1e30f;
        if (j0 + 16 + l15 > row) v1 = -1e30f;
        if (j0 + 32 + l15 > row) v2 = -1e30f;
        if (j0 + 48 + l15 > row) v3 = -1e30f;
      }
      float mloc = fmaxf(fmaxf(v0, v1), fmaxf(v2, v3));
      float m = mrun[r];
      if (!__all(mloc <= m + 8.0f)) {
        float mx = mloc;
        mx = fmaxf(mx, __shfl_xor(mx, 1));
        mx = fmaxf(mx, __shfl_xor(mx, 2));
        mx = fmaxf(mx, __shfl_xor(mx, 4));
        mx = fmaxf(mx, __shfl_xor(mx, 8));
        float mn = fmaxf(m, mx);
        float sc2 = exp2_fast(m - mn);
        lrun[r] *= sc2;
#pragma unroll
        for (int dt = 0; dt < 4; dt++) o[dt][r] *= sc2;
        m = mn; mrun[r] = mn;
      }
      float e0 = exp2_fast(v0 - m), e1 = exp2_fast(v1 - m);
      float e2 = exp2_fast(v2 - m), e3 = exp2_fast(v3 - m);
      lrun[r] += (e0 + e1) + (e2 + e3);
      u32x2 pkq = { pk_bf16(e0, e1), pk_bf16(e2, e3) };
      int prow = g * 4 + r;
      int byt = prow * 128 + ((((l15 >> 1) ^ (prow & 7)) << 4)) + (l15 & 1) * 8;
      *(u32x2*)((char*)pw + byt) = pkq;
    }

    const u16* vt = Vt[cur];
    bf16x8 pf0 = *(const bf16x8*)((char*)pw + l15 * 128 + (((g) ^ (l15 & 7)) << 4));
    bf16x8 pf1 = *(const bf16x8*)((char*)pw + l15 * 128 + (((4 + g) ^ (l15 & 7)) << 4));
#pragma unroll
    for (int dt = 0; dt < 4; dt++) {
      int d = dt * 16 + l15;
      bf16x8 vf0 = *(const bf16x8*)(vt + d * 72 + g * 8);
      bf16x8 vf1 = *(const bf16x8*)(vt + d * 72 + 32 + g * 8);
      o[dt] = __builtin_amdgcn_mfma_f32_16x16x32_bf16(pf0, vf0, o[dt], 0, 0, 0);
      o[dt] = __builtin_amdgcn_mfma_f32_16x16x32_bf16(pf1, vf1, o[dt], 0, 0, 0);
    }

    if (more && tid < 128) {
#pragma unroll
      for (int e = 0; e < 8; e++) {
        int d = dg * 8 + e;
        u32x2 wq = { (unsigned)vreg[0][e] | ((unsigned)vreg[1][e] << 16),
                     (unsigned)vreg[2][e] | ((unsigned)vreg[3][e] << 16) };
        *(u32x2*)(&Vt[cur ^ 1][d * 72 + kq * 4]) = wq;
      }
    }
    __syncthreads();
  }

#pragma unroll
  for (int r = 0; r < 4; r++) {
    float ls = lrun[r];
    ls += __shfl_xor(ls, 1); ls += __shfl_xor(ls, 2);
    ls += __shfl_xor(ls, 4); ls += __shfl_xor(ls, 8);
    float inv = 1.0f / ls;
    int row = q0 + g * 4 + r;
    u16* orow = out + (long)(b * T_ + row) * C_ + h * 64;
#pragma unroll
    for (int dt = 0; dt < 4; dt++)
      orow[dt * 16 + l15] = f2b(o[dt][r] * inv);
  }
}

// ---------------- host launcher ----------------
extern "C" void kernel_launch(void* const* d_in, const int* in_sizes, int n_in,
                              void* d_out, int out_size, void* d_ws, size_t ws_size,
                              hipStream_t stream) {
  const int*   idx    = (const int*)  d_in[0];
  const float* wte    = (const float*)d_in[1];
  const float* wpe    = (const float*)d_in[2];
  const float* ln1w   = (const float*)d_in[3];
  const float* ln1b   = (const float*)d_in[4];
  const float* wattn  = (const float*)d_in[5];
  const float* wcproj = (const float*)d_in[6];
  const float* ln2w   = (const float*)d_in[7];
  const float* ln2b   = (const float*)d_in[8];
  const float* wfc    = (const float*)d_in[9];
  const float* wproj2 = (const float*)d_in[10];
  const float* lnfw   = (const float*)d_in[11];
  const float* lnfb   = (const float*)d_in[12];
  float* out = (float*)d_out;

  char* p = (char*)d_ws;
  size_t off = 0;
  auto alloc = [&](size_t bytes) -> void* {
    void* r = p + off; off += (bytes + 255) & ~(size_t)255; return r;
  };
  float* x    = (float*)alloc((size_t)M_ * C_ * 4);
  u16* xn     = (u16*)alloc((size_t)M_ * C_ * 2);
  u16* qkvb   = (u16*)alloc((size_t)M_ * 3 * C_ * 2);
  u16* attb   = (u16*)alloc((size_t)M_ * C_ * 2);
  u16* hb     = (u16*)alloc((size_t)M_ * FF_ * 2);
  u16* wteB   = (u16*)alloc((size_t)V_ * C_ * 2);
  u16* wattnB = (u16*)alloc((size_t)L_ * 3 * C_ * C_ * 2);
  u16* wprojB = (u16*)alloc((size_t)L_ * C_ * C_ * 2);
  u16* wfcB   = (u16*)alloc((size_t)L_ * FF_ * C_ * 2);
  u16* wp2B   = (u16*)alloc((size_t)L_ * C_ * FF_ * 2);
  if (off > ws_size) return;

  CvtArgs ca;
  ca.s[0] = (const f32x4*)wte;    ca.d[0] = (u16x4*)wteB;
  ca.s[1] = (const f32x4*)wattn;  ca.d[1] = (u16x4*)wattnB;
  ca.s[2] = (const f32x4*)wcproj; ca.d[2] = (u16x4*)wprojB;
  ca.s[3] = (const f32x4*)wfc;    ca.d[3] = (u16x4*)wfcB;
  ca.s[4] = (const f32x4*)wproj2; ca.d[4] = (u16x4*)wp2B;
  cvt_all_k<<<dim3(2048), dim3(256), 0, stream>>>(ca);

  embed_k<<<dim3(M_ * C_ / 4 / 256), dim3(256), 0, stream>>>(idx, wte, wpe, x);

  for (int l = 0; l < L_; l++) {
    ln_k<<<dim3(M_ / 4), dim3(256), 0, stream>>>(x, ln1w + l * C_, ln1b + l * C_, xn);
    gemm_bt_k<0, 64, 128><<<dim3(768), dim3(256), 0, stream>>>(
        xn, wattnB + (size_t)l * 3 * C_ * C_, qkvb, nullptr, 3 * C_, C_, 3 * C_);
    attn_k<<<dim3(32, B_ * H_), dim3(256), 0, stream>>>(qkvb, attb);
    gemm_bt64_k<<<dim3(512), dim3(256), 0, stream>>>(
        attb, wprojB + (size_t)l * C_ * C_, x, C_, C_, C_);
    ln_k<<<dim3(M_ / 4), dim3(256), 0, stream>>>(x, ln2w + l * C_, ln2b + l * C_, xn);
    gemm_bt_k<2, 128, 128><<<dim3(512), dim3(256), 0, stream>>>(
        xn, wfcB + (size_t)l * FF_ * C_, hb, nullptr, FF_, C_, FF_);
    gemm_bt64_k<<<dim3(512), dim3(256), 0, stream>>>(
        hb, wp2B + (size_t)l * C_ * FF_, x, C_, FF_, C_);
  }
  ln_k<<<dim3(M_ / 4), dim3(256), 0, stream>>>(x, lnfw, lnfb, xn);
  gemm_lmhead_k<<<dim3(8 * 786), dim3(512), 0, stream>>>(xn, wteB, out, V_);
}

// Round 12
// 1218.020 us; speedup vs baseline: 1.3334x; 1.0005x over previous
//
#include <hip/hip_runtime.h>

typedef unsigned short u16;
typedef short bf16x8 __attribute__((ext_vector_type(8)));
typedef float f32x4 __attribute__((ext_vector_type(4)));
typedef unsigned short u16x4 __attribute__((ext_vector_type(4)));
typedef unsigned short u16x8 __attribute__((ext_vector_type(8)));
typedef unsigned int u32x2 __attribute__((ext_vector_type(2)));

#define B_ 2
#define T_ 2048
#define C_ 512
#define H_ 8
#define FF_ 2048
#define L_ 6
#define V_ 50257
#define M_ (B_*T_)

__device__ __forceinline__ u16 f2b(float f) {
  union { float f; unsigned u; } v; v.f = f;
  unsigned r = v.u + 0x7FFFu + ((v.u >> 16) & 1u);
  return (u16)(r >> 16);
}
__device__ __forceinline__ float b2f(u16 u) {
  union { unsigned u; float f; } v; v.u = ((unsigned)u) << 16; return v.f;
}
__device__ __forceinline__ unsigned pk_bf16(float lo, float hi) {
  unsigned r;
  asm volatile("v_cvt_pk_bf16_f32 %0, %1, %2" : "=v"(r) : "v"(lo), "v"(hi));
  return r;
}
__device__ __forceinline__ float exp2_fast(float x) {
  float r; asm("v_exp_f32 %0, %1" : "=v"(r) : "v"(x)); return r;
}
__device__ __forceinline__ float rcp_fast(float x) {
  float r; asm("v_rcp_f32 %0, %1" : "=v"(r) : "v"(x)); return r;
}

__device__ __forceinline__ void async16(const void* g, void* l) {
  __builtin_amdgcn_global_load_lds((const __attribute__((address_space(1))) unsigned int*)g,
                                   (__attribute__((address_space(3))) unsigned int*)l, 16, 0, 0);
}

template<int N> __device__ __forceinline__ void vwait() {
  if constexpr (N == 0) asm volatile("s_waitcnt vmcnt(0)" ::: "memory");
  else if constexpr (N == 2) asm volatile("s_waitcnt vmcnt(2)" ::: "memory");
  else if constexpr (N == 3) asm volatile("s_waitcnt vmcnt(3)" ::: "memory");
  else if constexpr (N == 4) asm volatile("s_waitcnt vmcnt(4)" ::: "memory");
}

__device__ __forceinline__ bf16x8 scale8(u16x8 v, float s) {
  union { bf16x8 b; unsigned u[4]; } r;
#pragma unroll
  for (int i = 0; i < 4; i++)
    r.u[i] = pk_bf16(b2f(v[2*i]) * s, b2f(v[2*i+1]) * s);
  return r.b;
}

__device__ __forceinline__ float gelu_f(float f) {
  float u = f * f;
  float inner = f * (0.7978845608028654f + 0.03567740814183056f * u);
  inner = fminf(fmaxf(inner, -15.f), 15.f);
  float a = exp2_fast(2.8853900817779268f * inner);
  return f * a * rcp_fast(a + 1.0f);
}

// ---------------- fp32 -> bf16 conversion (all 5 weight tensors, 1 launch) ----
struct CvtArgs { const f32x4* s[5]; u16x4* d[5]; };
__global__ void cvt_all_k(CvtArgs a) {
  const int sizes[5] = { V_*C_/4, L_*3*C_*C_/4, L_*C_*C_/4, L_*FF_*C_/4, L_*C_*FF_/4 };
  int gid = blockIdx.x * blockDim.x + threadIdx.x;
  int stride = gridDim.x * blockDim.x;
#pragma unroll
  for (int seg = 0; seg < 5; seg++) {
    const f32x4* src = a.s[seg];
    u16x4* dst = a.d[seg];
    for (int i = gid; i < sizes[seg]; i += stride) {
      f32x4 v = src[i];
      u16x4 o;
      o[0] = f2b(v[0]); o[1] = f2b(v[1]); o[2] = f2b(v[2]); o[3] = f2b(v[3]);
      dst[i] = o;
    }
  }
}

// ---------------- embedding ----------------
__global__ void embed_k(const int* __restrict__ idx, const float* __restrict__ wte,
                        const float* __restrict__ wpe, float* __restrict__ x) {
  int t = blockIdx.x * 256 + threadIdx.x;
  int row = t >> 7;
  int c4 = t & 127;
  int tok = idx[row];
  int pos = row & (T_ - 1);
  f32x4 a = ((const f32x4*)(wte + (long)tok * C_))[c4];
  f32x4 p = ((const f32x4*)(wpe + (long)pos * C_))[c4];
  ((f32x4*)x)[t] = a + p;
}

// ---------------- layernorm ----------------
__global__ void ln_k(const float* __restrict__ x, const float* __restrict__ w,
                     const float* __restrict__ b, u16* __restrict__ out) {
  int wv = threadIdx.x >> 6;
  int lane = threadIdx.x & 63;
  int row = blockIdx.x * 4 + wv;
  const f32x4* xr = (const f32x4*)(x + (long)row * C_);
  f32x4 v0 = xr[lane * 2], v1 = xr[lane * 2 + 1];
  float s = 0.f, s2 = 0.f;
#pragma unroll
  for (int j = 0; j < 4; j++) { s += v0[j] + v1[j]; s2 += v0[j]*v0[j] + v1[j]*v1[j]; }
#pragma unroll
  for (int off = 32; off >= 1; off >>= 1) { s += __shfl_xor(s, off); s2 += __shfl_xor(s2, off); }
  float mu = s * (1.f / C_);
  float inv = rsqrtf(s2 * (1.f / C_) - mu * mu + 1e-5f);
  const f32x4* wr = (const f32x4*)w;
  const f32x4* br = (const f32x4*)b;
  f32x4 w0 = wr[lane*2], w1 = wr[lane*2+1], b0 = br[lane*2], b1 = br[lane*2+1];
  u16x8 o;
#pragma unroll
  for (int j = 0; j < 4; j++) {
    o[j]     = f2b((v0[j] - mu) * inv * w0[j] + b0[j]);
    o[j + 4] = f2b((v1[j] - mu) * inv * w1[j] + b1[j]);
  }
  *(u16x8*)(out + (long)row * C_ + lane * 8) = o;
}

// ---------------- GEMM: C[M,N] = A[M,K] * B[N,K]^T (BK=32) ----------------
// 3-buffer ring, ONE barrier/iter, stage-before-compute, counted vmcnt.
// XCD-bijective m-slice mapping.
// EPI: 0 = bf16 store, 2 = gelu(tanh-form)->bf16
template<int EPI, int BM, int BN>
__global__ __launch_bounds__(256) void gemm_bt_k(
    const u16* __restrict__ A, const u16* __restrict__ Bw,
    u16* __restrict__ Cb, float* __restrict__ Cf,
    int N, int K, int ldc)
{
  constexpr int MT = BM / 32;
  constexpr int NT = BN / 32;
  constexpr int AJ = BM / 64;
  constexpr int BJ = BN / 64;
  constexpr int LPT = AJ + BJ;
  constexpr int MX = (M_ / BM) / 8;   // m-tiles per XCD
  __shared__ __align__(16) u16 sA[3][BM * 32];
  __shared__ __align__(16) u16 sB[3][BN * 32];
  const int bid = blockIdx.x;
  const int xc = bid & 7;
  const int jj = bid >> 3;
  const int m0 = (xc * MX + (jj % MX)) * BM;
  const int n0 = (jj / MX) * BN;
  const int tid = threadIdx.x;
  const int w = tid >> 6;
  const int lane = tid & 63;
  const int wm = (w >> 1) * (BM / 2);
  const int wn = (w & 1) * (BN / 2);
  const int g = lane >> 4;
  const int l15 = lane & 15;
  const int sw3 = l15 & 3;

  f32x4 acc[MT][NT] = {};

  const int nk = K >> 5;
  const int ksw = ((tid & 3) ^ ((tid >> 2) & 3)) * 8;
  const u16* gA[AJ];
  const u16* gB[BJ];
#pragma unroll
  for (int j = 0; j < AJ; j++)
    gA[j] = A + (long)(m0 + (tid >> 2) + j * 64) * K + ksw;
#pragma unroll
  for (int j = 0; j < BJ; j++)
    gB[j] = Bw + (long)(n0 + (tid >> 2) + j * 64) * K + ksw;

  auto stage = [&](int buf, int kt) {
    int ko = kt << 5;
#pragma unroll
    for (int j = 0; j < AJ; j++)
      async16(gA[j] + ko, &sA[buf][(j * 256 + w * 64) * 8]);
#pragma unroll
    for (int j = 0; j < BJ; j++)
      async16(gB[j] + ko, &sB[buf][(j * 256 + w * 64) * 8]);
  };

  stage(0, 0);
  stage(1, 1);
  int cur = 0, nxt = 2;
  for (int kt = 0; kt < nk; kt++) {
    if (kt + 1 < nk) vwait<LPT>(); else vwait<0>();
    __builtin_amdgcn_s_barrier();
    if (kt + 2 < nk) stage(nxt, kt + 2);
    const u16* pa = sA[cur];
    const u16* pb = sB[cur];
    bf16x8 af[MT], bfr[NT];
#pragma unroll
    for (int mt = 0; mt < MT; mt++)
      af[mt] = *(const bf16x8*)(pa + (wm + mt * 16 + l15) * 32 + ((g ^ sw3) * 8));
#pragma unroll
    for (int nt = 0; nt < NT; nt++)
      bfr[nt] = *(const bf16x8*)(pb + (wn + nt * 16 + l15) * 32 + ((g ^ sw3) * 8));
#pragma unroll
    for (int mt = 0; mt < MT; mt++)
#pragma unroll
      for (int nt = 0; nt < NT; nt++)
        acc[mt][nt] = __builtin_amdgcn_mfma_f32_16x16x32_bf16(af[mt], bfr[nt], acc[mt][nt], 0, 0, 0);
    cur = (cur == 2) ? 0 : cur + 1;
    nxt = (nxt == 2) ? 0 : nxt + 1;
  }

#pragma unroll
  for (int mt = 0; mt < MT; mt++) {
    int m = m0 + wm + mt * 16 + g * 4;
#pragma unroll
    for (int nt = 0; nt < NT; nt++) {
      int n = n0 + wn + nt * 16 + l15;
      f32x4 v = acc[mt][nt];
#pragma unroll
      for (int r = 0; r < 4; r++) {
        long ci = (long)(m + r) * ldc + n;
        if (EPI == 0) {
          Cb[ci] = f2b(v[r]);
        } else {
          Cb[ci] = f2b(gelu_f(v[r]));
        }
      }
    }
  }
}

// ---------------- GEMM 64x64, BK=64, fp32 residual-add epilogue ----------------
// Same XCD m-slice mapping (MX=8).
__global__ __launch_bounds__(256) void gemm_bt64_k(
    const u16* __restrict__ A, const u16* __restrict__ Bw,
    float* __restrict__ Cf, int N, int K, int ldc)
{
  __shared__ __align__(16) u16 sA[3][64 * 64];
  __shared__ __align__(16) u16 sB[3][64 * 64];
  const int bid = blockIdx.x;
  const int xc = bid & 7;
  const int jj = bid >> 3;
  const int m0 = (xc * 8 + (jj & 7)) * 64;
  const int n0 = (jj >> 3) * 64;
  const int tid = threadIdx.x;
  const int w = tid >> 6;
  const int lane = tid & 63;
  const int wm = (w >> 1) * 32;
  const int wn = (w & 1) * 32;
  const int g = lane >> 4;
  const int l15 = lane & 15;
  const int sw3 = l15 & 3;

  f32x4 acc[2][2] = {};

  const int nk = K >> 6;
  const int srow = tid >> 3;
  const int sl = tid & 7;
  const int kcol = (((sl & 4) | ((sl & 3) ^ (srow & 3)))) * 8;
  const u16* gA[2];
  const u16* gB[2];
#pragma unroll
  for (int j = 0; j < 2; j++) {
    gA[j] = A + (long)(m0 + srow + j * 32) * K + kcol;
    gB[j] = Bw + (long)(n0 + srow + j * 32) * K + kcol;
  }

  auto stage = [&](int buf, int kt) {
    int ko = kt << 6;
#pragma unroll
    for (int j = 0; j < 2; j++)
      async16(gA[j] + ko, &sA[buf][(j * 256 + w * 64) * 8]);
#pragma unroll
    for (int j = 0; j < 2; j++)
      async16(gB[j] + ko, &sB[buf][(j * 256 + w * 64) * 8]);
  };

  stage(0, 0);
  stage(1, 1);
  int cur = 0, nxt = 2;
  for (int kt = 0; kt < nk; kt++) {
    if (kt + 1 < nk) vwait<4>(); else vwait<0>();
    __builtin_amdgcn_s_barrier();
    if (kt + 2 < nk) stage(nxt, kt + 2);
    const u16* pa = sA[cur];
    const u16* pb = sB[cur];
#pragma unroll
    for (int h = 0; h < 2; h++) {
      bf16x8 af[2], bfr[2];
#pragma unroll
      for (int mt = 0; mt < 2; mt++)
        af[mt] = *(const bf16x8*)(pa + (wm + mt * 16 + l15) * 64 + (((g ^ sw3) + h * 4) * 8));
#pragma unroll
      for (int nt = 0; nt < 2; nt++)
        bfr[nt] = *(const bf16x8*)(pb + (wn + nt * 16 + l15) * 64 + (((g ^ sw3) + h * 4) * 8));
#pragma unroll
      for (int mt = 0; mt < 2; mt++)
#pragma unroll
        for (int nt = 0; nt < 2; nt++)
          acc[mt][nt] = __builtin_amdgcn_mfma_f32_16x16x32_bf16(af[mt], bfr[nt], acc[mt][nt], 0, 0, 0);
    }
    cur = (cur == 2) ? 0 : cur + 1;
    nxt = (nxt == 2) ? 0 : nxt + 1;
  }

#pragma unroll
  for (int mt = 0; mt < 2; mt++) {
    int m = m0 + wm + mt * 16 + g * 4;
#pragma unroll
    for (int nt = 0; nt < 2; nt++) {
      int n = n0 + wn + nt * 16 + l15;
      f32x4 v = acc[mt][nt];
#pragma unroll
      for (int r = 0; r < 4; r++)
        Cf[(long)(m + r) * ldc + n] += v[r];
    }
  }
}

// ---------------- lm_head GEMM v2: 128x128, 256 threads, 3 blocks/CU ----------
// Same proven 3-buf single-barrier ring as gemm_bt_k (LPT=4), fp32 N-clamped
// store epilogue. Grid 12576 = 8 XCD x (4 m-local x 393 n), m-FASTEST within
// XCD: the 4 m-blocks of one n-tile share the B-slice (128KB L2-hot) and
// their A-slices stay L2-hot; B streams HBM once per XCD (= R9's measured
// 413MB FETCH). Finer blocks -> 3/CU phase-staggered overlap of
// stage/compute/store (lm_head was latency-bound: MfmaUtil 10%, HBM 31%).
__global__ __launch_bounds__(256) void gemm_lmhead_k(
    const u16* __restrict__ A, const u16* __restrict__ Bw,
    float* __restrict__ Cf, int N)
{
  constexpr int LPT = 4;
  __shared__ __align__(16) u16 sA[3][128 * 32];
  __shared__ __align__(16) u16 sB[3][128 * 32];
  const int K = 512;
  const int bid = blockIdx.x;           // 8 * 1572
  const int xc = bid & 7;
  const int j = bid >> 3;
  const int mloc = j & 3;
  const int nidx = j >> 2;              // 0..392
  const int m0 = (xc * 4 + mloc) * 128;
  const int n0 = nidx * 128;
  const int tid = threadIdx.x;
  const int w = tid >> 6;
  const int lane = tid & 63;
  const int wm = (w >> 1) * 64;
  const int wn = (w & 1) * 64;
  const int g = lane >> 4;
  const int l15 = lane & 15;
  const int sw3 = l15 & 3;

  f32x4 acc[4][4] = {};

  const int ksw = ((tid & 3) ^ ((tid >> 2) & 3)) * 8;
  const u16* gA[2];
  const u16* gB[2];
#pragma unroll
  for (int jj = 0; jj < 2; jj++) {
    gA[jj] = A + (long)(m0 + (tid >> 2) + jj * 64) * K + ksw;
    int brow = n0 + (tid >> 2) + jj * 64; if (brow > N - 1) brow = N - 1;
    gB[jj] = Bw + (long)brow * K + ksw;
  }

  auto stage = [&](int buf, int kt) {
    int ko = kt << 5;
#pragma unroll
    for (int jj = 0; jj < 2; jj++)
      async16(gA[jj] + ko, &sA[buf][(jj * 256 + w * 64) * 8]);
#pragma unroll
    for (int jj = 0; jj < 2; jj++)
      async16(gB[jj] + ko, &sB[buf][(jj * 256 + w * 64) * 8]);
  };

  stage(0, 0);
  stage(1, 1);
  int cur = 0, nxt = 2;
  const int nk = K >> 5;   // 16
  for (int kt = 0; kt < nk; kt++) {
    if (kt + 1 < nk) vwait<LPT>(); else vwait<0>();
    __builtin_amdgcn_s_barrier();
    if (kt + 2 < nk) stage(nxt, kt + 2);
    const u16* pa = sA[cur];
    const u16* pb = sB[cur];
    bf16x8 af[4], bfr[4];
#pragma unroll
    for (int mt = 0; mt < 4; mt++)
      af[mt] = *(const bf16x8*)(pa + (wm + mt * 16 + l15) * 32 + ((g ^ sw3) * 8));
#pragma unroll
    for (int nt = 0; nt < 4; nt++)
      bfr[nt] = *(const bf16x8*)(pb + (wn + nt * 16 + l15) * 32 + ((g ^ sw3) * 8));
    __builtin_amdgcn_s_setprio(1);
#pragma unroll
    for (int mt = 0; mt < 4; mt++)
#pragma unroll
      for (int nt = 0; nt < 4; nt++)
        acc[mt][nt] = __builtin_amdgcn_mfma_f32_16x16x32_bf16(af[mt], bfr[nt], acc[mt][nt], 0, 0, 0);
    __builtin_amdgcn_s_setprio(0);
    cur = (cur == 2) ? 0 : cur + 1;
    nxt = (nxt == 2) ? 0 : nxt + 1;
  }

#pragma unroll
  for (int mt = 0; mt < 4; mt++) {
    int m = m0 + wm + mt * 16 + g * 4;
#pragma unroll
    for (int nt = 0; nt < 4; nt++) {
      int n = n0 + wn + nt * 16 + l15;
      f32x4 v = acc[mt][nt];
      if (n < N) {
#pragma unroll
        for (int r = 0; r < 4; r++)
          Cf[(long)(m + r) * N + n] = v[r];
      }
    }
  }
}

// ---------------- flash attention: 4 waves / 64-row qblk ----------------
__global__ __launch_bounds__(256) void attn_k(const u16* __restrict__ qkv, u16* __restrict__ out) {
  const int bh = blockIdx.y;
  const int b = bh >> 3;
  const int h = bh & 7;
  const int tid = threadIdx.x;
  const int wv = tid >> 6;
  const int lane = tid & 63;
  const int g = lane >> 4;
  const int l15 = lane & 15;
  const int qblk = 31 - blockIdx.x;

  __shared__ __align__(16) u16 Ks[2][64 * 64];
  __shared__ __align__(16) u16 Vt[2][64 * 72];
  __shared__ __align__(16) u16 Ps[4][16 * 64];

  const long base = (long)b * T_ * 1536;
  const u16* kbase = qkv + base + 512 + h * 64;
  const u16* vbase = qkv + base + 1024 + h * 64;
  const int kq = tid & 15;
  const int dg = (tid >> 4) & 7;
  const float qscale = 0.18033688011112042f;  // 1/sqrt(64) * log2(e)

  const int q0 = qblk * 64 + wv * 16;

  const u16* qrow = qkv + base + (long)(q0 + l15) * 1536 + h * 64;
  bf16x8 qf0 = scale8(*(const u16x8*)(qrow + g * 8), qscale);
  bf16x8 qf1 = scale8(*(const u16x8*)(qrow + 32 + g * 8), qscale);

  f32x4 o[4] = {};
  float mrun[4] = {-1e30f, -1e30f, -1e30f, -1e30f};
  float lrun[4] = {0.f, 0.f, 0.f, 0.f};
  const int kvend = qblk * 64 + 64;

  u16x8 vreg[4];
#pragma unroll
  for (int i = 0; i < 2; i++) {
    int chunk = i * 256 + tid;
    int row = chunk >> 3, c8 = chunk & 7;
    async16(kbase + (long)row * 1536 + (c8 ^ (row & 7)) * 8,
            &Ks[0][(i * 256 + wv * 64) * 8]);
  }
  if (tid < 128) {
#pragma unroll
    for (int t = 0; t < 4; t++)
      vreg[t] = *(const u16x8*)(vbase + (long)(kq + 16 * t) * 1536 + dg * 8);
#pragma unroll
    for (int e = 0; e < 8; e++) {
      int d = dg * 8 + e;
      u32x2 wq = { (unsigned)vreg[0][e] | ((unsigned)vreg[1][e] << 16),
                   (unsigned)vreg[2][e] | ((unsigned)vreg[3][e] << 16) };
      *(u32x2*)(&Vt[0][d * 72 + kq * 4]) = wq;
    }
  }
  __syncthreads();

  int cur = 0;
  for (int j0 = 0; j0 < kvend; j0 += 64, cur ^= 1) {
    const bool more = (j0 + 64) < kvend;
    if (more) {
      int jn = j0 + 64;
#pragma unroll
      for (int i = 0; i < 2; i++) {
        int chunk = i * 256 + tid;
        int row = chunk >> 3, c8 = chunk & 7;
        async16(kbase + (long)(jn + row) * 1536 + (c8 ^ (row & 7)) * 8,
                &Ks[cur ^ 1][(i * 256 + wv * 64) * 8]);
      }
      if (tid < 128) {
#pragma unroll
        for (int t = 0; t < 4; t++)
          vreg[t] = *(const u16x8*)(vbase + (long)(jn + kq + 16 * t) * 1536 + dg * 8);
      }
    }

    f32x4 s[4] = {};
    const u16* kp = Ks[cur];
#pragma unroll
    for (int t = 0; t < 4; t++) {
      int row = t * 16 + l15;
      const u16* kr = kp + row * 64;
      bf16x8 k0 = *(const bf16x8*)(kr + ((g ^ (row & 7)) * 8));
      bf16x8 k1 = *(const bf16x8*)(kr + (((4 + g) ^ (row & 7)) * 8));
      s[t] = __builtin_amdgcn_mfma_f32_16x16x32_bf16(qf0, k0, s[t], 0, 0, 0);
      s[t] = __builtin_amdgcn_mfma_f32_16x16x32_bf16(qf1, k1, s[t], 0, 0, 0);
    }

    const bool diag = (j0 + 64) == kvend;
    u16* pw = Ps[wv];
#pragma unroll
    for (int r = 0; r < 4; r++) {
      int row = q0 + g * 4 + r;
      float v0 = s[0][r], v1 = s[1][r], v2 = s[2][r], v3 = s[3][r];
      if (diag) {
        if (j0 +      l15 > row) v0 = -1e30f;
        if (j0 + 16 + l15 > row) v1 = -1e30f;
        if (j0 + 32 + l15 > row) v2 = -1e30f;
        if (j0 + 48 + l15 > row) v3 = -1e30f;
      }
      float mloc = fmaxf(fmaxf(v0, v1), fmaxf(v2, v3));
      float m = mrun[r];
      if (!__all(mloc <= m + 8.0f)) {
        float mx = mloc;
        mx = fmaxf(mx, __shfl_xor(mx, 1));
        mx = fmaxf(mx, __shfl_xor(mx, 2));
        mx = fmaxf(mx, __shfl_xor(mx, 4));
        mx = fmaxf(mx, __shfl_xor(mx, 8));
        float mn = fmaxf(m, mx);
        float sc2 = exp2_fast(m - mn);
        lrun[r] *= sc2;
#pragma unroll
        for (int dt = 0; dt < 4; dt++) o[dt][r] *= sc2;
        m = mn; mrun[r] = mn;
      }
      float e0 = exp2_fast(v0 - m), e1 = exp2_fast(v1 - m);
      float e2 = exp2_fast(v2 - m), e3 = exp2_fast(v3 - m);
      lrun[r] += (e0 + e1) + (e2 + e3);
      u32x2 pkq = { pk_bf16(e0, e1), pk_bf16(e2, e3) };
      int prow = g * 4 + r;
      int byt = prow * 128 + ((((l15 >> 1) ^ (prow & 7)) << 4)) + (l15 & 1) * 8;
      *(u32x2*)((char*)pw + byt) = pkq;
    }

    const u16* vt = Vt[cur];
    bf16x8 pf0 = *(const bf16x8*)((char*)pw + l15 * 128 + (((g) ^ (l15 & 7)) << 4));
    bf16x8 pf1 = *(const bf16x8*)((char*)pw + l15 * 128 + (((4 + g) ^ (l15 & 7)) << 4));
#pragma unroll
    for (int dt = 0; dt < 4; dt++) {
      int d = dt * 16 + l15;
      bf16x8 vf0 = *(const bf16x8*)(vt + d * 72 + g * 8);
      bf16x8 vf1 = *(const bf16x8*)(vt + d * 72 + 32 + g * 8);
      o[dt] = __builtin_amdgcn_mfma_f32_16x16x32_bf16(pf0, vf0, o[dt], 0, 0, 0);
      o[dt] = __builtin_amdgcn_mfma_f32_16x16x32_bf16(pf1, vf1, o[dt], 0, 0, 0);
    }

    if (more && tid < 128) {
#pragma unroll
      for (int e = 0; e < 8; e++) {
        int d = dg * 8 + e;
        u32x2 wq = { (unsigned)vreg[0][e] | ((unsigned)vreg[1][e] << 16),
                     (unsigned)vreg[2][e] | ((unsigned)vreg[3][e] << 16) };
        *(u32x2*)(&Vt[cur ^ 1][d * 72 + kq * 4]) = wq;
      }
    }
    __syncthreads();
  }

#pragma unroll
  for (int r = 0; r < 4; r++) {
    float ls = lrun[r];
    ls += __shfl_xor(ls, 1); ls += __shfl_xor(ls, 2);
    ls += __shfl_xor(ls, 4); ls += __shfl_xor(ls, 8);
    float inv = 1.0f / ls;
    int row = q0 + g * 4 + r;
    u16* orow = out + (long)(b * T_ + row) * C_ + h * 64;
#pragma unroll
    for (int dt = 0; dt < 4; dt++)
      orow[dt * 16 + l15] = f2b(o[dt][r] * inv);
  }
}

// ---------------- host launcher ----------------
extern "C" void kernel_launch(void* const* d_in, const int* in_sizes, int n_in,
                              void* d_out, int out_size, void* d_ws, size_t ws_size,
                              hipStream_t stream) {
  const int*   idx    = (const int*)  d_in[0];
  const float* wte    = (const float*)d_in[1];
  const float* wpe    = (const float*)d_in[2];
  const float* ln1w   = (const float*)d_in[3];
  const float* ln1b   = (const float*)d_in[4];
  const float* wattn  = (const float*)d_in[5];
  const float* wcproj = (const float*)d_in[6];
  const float* ln2w   = (const float*)d_in[7];
  const float* ln2b   = (const float*)d_in[8];
  const float* wfc    = (const float*)d_in[9];
  const float* wproj2 = (const float*)d_in[10];
  const float* lnfw   = (const float*)d_in[11];
  const float* lnfb   = (const float*)d_in[12];
  float* out = (float*)d_out;

  char* p = (char*)d_ws;
  size_t off = 0;
  auto alloc = [&](size_t bytes) -> void* {
    void* r = p + off; off += (bytes + 255) & ~(size_t)255; return r;
  };
  float* x    = (float*)alloc((size_t)M_ * C_ * 4);
  u16* xn     = (u16*)alloc((size_t)M_ * C_ * 2);
  u16* qkvb   = (u16*)alloc((size_t)M_ * 3 * C_ * 2);
  u16* attb   = (u16*)alloc((size_t)M_ * C_ * 2);
  u16* hb     = (u16*)alloc((size_t)M_ * FF_ * 2);
  u16* wteB   = (u16*)alloc((size_t)V_ * C_ * 2);
  u16* wattnB = (u16*)alloc((size_t)L_ * 3 * C_ * C_ * 2);
  u16* wprojB = (u16*)alloc((size_t)L_ * C_ * C_ * 2);
  u16* wfcB   = (u16*)alloc((size_t)L_ * FF_ * C_ * 2);
  u16* wp2B   = (u16*)alloc((size_t)L_ * C_ * FF_ * 2);
  if (off > ws_size) return;

  CvtArgs ca;
  ca.s[0] = (const f32x4*)wte;    ca.d[0] = (u16x4*)wteB;
  ca.s[1] = (const f32x4*)wattn;  ca.d[1] = (u16x4*)wattnB;
  ca.s[2] = (const f32x4*)wcproj; ca.d[2] = (u16x4*)wprojB;
  ca.s[3] = (const f32x4*)wfc;    ca.d[3] = (u16x4*)wfcB;
  ca.s[4] = (const f32x4*)wproj2; ca.d[4] = (u16x4*)wp2B;
  cvt_all_k<<<dim3(2048), dim3(256), 0, stream>>>(ca);

  embed_k<<<dim3(M_ * C_ / 4 / 256), dim3(256), 0, stream>>>(idx, wte, wpe, x);

  for (int l = 0; l < L_; l++) {
    ln_k<<<dim3(M_ / 4), dim3(256), 0, stream>>>(x, ln1w + l * C_, ln1b + l * C_, xn);
    gemm_bt_k<0, 64, 128><<<dim3(768), dim3(256), 0, stream>>>(
        xn, wattnB + (size_t)l * 3 * C_ * C_, qkvb, nullptr, 3 * C_, C_, 3 * C_);
    attn_k<<<dim3(32, B_ * H_), dim3(256), 0, stream>>>(qkvb, attb);
    gemm_bt64_k<<<dim3(512), dim3(256), 0, stream>>>(
        attb, wprojB + (size_t)l * C_ * C_, x, C_, C_, C_);
    ln_k<<<dim3(M_ / 4), dim3(256), 0, stream>>>(x, ln2w + l * C_, ln2b + l * C_, xn);
    gemm_bt_k<2, 128, 128><<<dim3(512), dim3(256), 0, stream>>>(
        xn, wfcB + (size_t)l * FF_ * C_, hb, nullptr, FF_, C_, FF_);
    gemm_bt64_k<<<dim3(512), dim3(256), 0, stream>>>(
        hb, wp2B + (size_t)l * C_ * FF_, x, C_, FF_, C_);
  }
  ln_k<<<dim3(M_ / 4), dim3(256), 0, stream>>>(x, lnfw, lnfb, xn);
  gemm_lmhead_k<<<dim3(8 * 1572), dim3(256), 0, stream>>>(xn, wteB, out, V_);
}